// Round 17
// baseline (553.822 us; speedup 1.0000x reference)
//
#include <hip/hip_runtime.h>
#include <hip/hip_bf16.h>

#define NN 100000
#define EE 300000
#define DD 256
#define HH 4
#define CC 64
#define LL 3
#define SCAN_CHUNK 1024

#define BK 64
#define MPAD 100096   // 782*128, padded row count for act

typedef __attribute__((ext_vector_type(8))) short bh8;    // 8 bf16 = 4 VGPR
typedef __attribute__((ext_vector_type(4))) float f32x4;

__device__ inline float bf2f(unsigned short u) {
    union { float f; unsigned int i; } c; c.i = ((unsigned int)u) << 16; return c.f;
}
__device__ inline unsigned short f2bf(float x) {
    __hip_bfloat16 b = __float2bfloat16(x);
    return *reinterpret_cast<unsigned short*>(&b);
}

// ---------------- CSR build ----------------

__global__ __launch_bounds__(256) void k_count(const int* __restrict__ dst, int* __restrict__ deg, int E_) {
    int e = blockIdx.x * 256 + threadIdx.x;
    if (e < E_) atomicAdd(&deg[dst[e]], 1);
}

__global__ __launch_bounds__(256) void k_scan1(const int* __restrict__ deg, int* __restrict__ bsum, int n) {
    int b = blockIdx.x;
    int base = b * SCAN_CHUNK;
    int t = threadIdx.x;
    int s = 0;
    for (int i = t; i < SCAN_CHUNK; i += 256) {
        int idx = base + i;
        if (idx < n) s += deg[idx];
    }
    __shared__ int sdata[256];
    sdata[t] = s;
    __syncthreads();
    for (int off = 128; off > 0; off >>= 1) {
        if (t < off) sdata[t] += sdata[t + off];
        __syncthreads();
    }
    if (t == 0) bsum[b] = sdata[0];
}

__global__ void k_scan2(const int* __restrict__ bsum, int* __restrict__ boff, int nb,
                        int* __restrict__ offsets, int n) {
    if (threadIdx.x == 0 && blockIdx.x == 0) {
        int run = 0;
        for (int i = 0; i < nb; i++) { boff[i] = run; run += bsum[i]; }
        offsets[n] = run;
    }
}

__global__ __launch_bounds__(256) void k_scan3(const int* __restrict__ deg, const int* __restrict__ boff,
                                               int* __restrict__ offsets, int n) {
    int b = blockIdx.x, t = threadIdx.x;
    int base = b * SCAN_CHUNK;
    int i0 = base + t * 4;
    int v[4]; int sum = 0;
    #pragma unroll
    for (int j = 0; j < 4; j++) {
        int idx = i0 + j;
        v[j] = (idx < n) ? deg[idx] : 0;
        sum += v[j];
    }
    __shared__ int sdata[256];
    sdata[t] = sum;
    __syncthreads();
    for (int off = 1; off < 256; off <<= 1) {
        int x = (t >= off) ? sdata[t - off] : 0;
        __syncthreads();
        sdata[t] += x;
        __syncthreads();
    }
    int excl = (t == 0) ? 0 : sdata[t - 1];
    int run = boff[b] + excl;
    #pragma unroll
    for (int j = 0; j < 4; j++) {
        int idx = i0 + j;
        if (idx < n) offsets[idx] = run;
        run += v[j];
    }
}

__global__ __launch_bounds__(256) void k_fill(const int* __restrict__ src, const int* __restrict__ dst,
                                              const int* __restrict__ ety, const float* __restrict__ efe,
                                              const int* __restrict__ offsets, int* __restrict__ cursor,
                                              int* __restrict__ csr_src, float* __restrict__ csr_feat, int E_) {
    int e = blockIdx.x * 256 + threadIdx.x;
    if (e < E_) {
        int d = dst[e];
        int pos = offsets[d] + atomicAdd(&cursor[d], 1);
        csr_src[pos] = src[e] | (ety[e] << 24);
        csr_feat[pos] = efe[e];
    }
}

// ---------------- weight prep: Wct[l][n][k] = W[l][k][n] as bf16 ----------------
__global__ __launch_bounds__(256) void k_cvtw(const float* __restrict__ Wl, const float* __restrict__ Wr,
                                              unsigned short* __restrict__ Wct) {
    int mat = blockIdx.z;
    int layer = mat >> 1, which = mat & 1;
    const float* src = (which ? Wr : Wl) + (size_t)layer * DD * DD;
    unsigned short* dst = Wct + (size_t)layer * 512 * DD + (size_t)which * DD * DD;
    int k0 = blockIdx.x * 64, n0 = blockIdx.y * 64;
    __shared__ float tile[64][65];
    int tx = threadIdx.x & 63, ty = threadIdx.x >> 6;
    #pragma unroll
    for (int i = 0; i < 16; i++) {
        int r = i * 4 + ty;
        tile[r][tx] = src[(size_t)(k0 + r) * DD + n0 + tx];
    }
    __syncthreads();
    #pragma unroll
    for (int i = 0; i < 16; i++) {
        int r = i * 4 + ty;
        dst[(size_t)(n0 + r) * DD + k0 + tx] = f2bf(tile[tx][r]);
    }
}

__global__ __launch_bounds__(256) void k_bias(const float* __restrict__ bl, const float* __restrict__ br,
                                              float* __restrict__ bc) {
    int i = blockIdx.x * 256 + threadIdx.x;
    if (i < LL * 512) {
        int l = i >> 9, j = i & 511;
        bc[i] = (j < 256) ? bl[l * DD + j] : br[l * DD + j - 256];
    }
}

// ---------------- pre-encoder: act = bf16(relu(x @ W0 + b0)) ----------------
__global__ __launch_bounds__(256) void k_preenc(const float* __restrict__ x, const float* __restrict__ W0,
                                                const float* __restrict__ b0, unsigned short* __restrict__ act) {
    __shared__ float xs[8][32];
    int t = threadIdx.x;
    int nb = blockIdx.x * 8;
    {
        int m = t >> 5, k = t & 31;
        xs[m][k] = x[(size_t)(nb + m) * 32 + k];
    }
    __syncthreads();
    float acc[8];
    float b = b0[t];
    #pragma unroll
    for (int m = 0; m < 8; m++) acc[m] = b;
    for (int k = 0; k < 32; k++) {
        float w = W0[k * DD + t];
        #pragma unroll
        for (int m = 0; m < 8; m++) acc[m] += xs[m][k] * w;
    }
    #pragma unroll
    for (int m = 0; m < 8; m++) {
        act[(size_t)(nb + m) * DD + t] = f2bf(fmaxf(acc[m], 0.f));
    }
}

// ---------------- MFMA GEMM v8: xlr[M,512] = act[M,256] @ Weff^T + beff ----------------
// BM=128 x full-N=512 per block (A read once; v2 structure with doubled M).
// 782 blocks (half of v2) -> half the staging phases and half the B-panel L2
// traffic; MFMA per block doubles (better stage:compute ratio). 8 waves, wave
// w owns cols [w*64,w*64+64) x all 128 rows -> acc[8][4]. LDS 92KB, 1 blk/CU
// (shown costless: 1-vs-2 blk/CU timed equal). Epilogue: two 64-row half
// passes through the Bs-reused stage (pitch 544), coalesced 16B stores.
__global__ __launch_bounds__(512) void k_gemm(const unsigned short* __restrict__ act,
                                              const unsigned short* __restrict__ Wct,
                                              const float* __restrict__ bc,
                                              unsigned short* __restrict__ xlr) {
    __shared__ short As[128][72];                  // 18432 B
    __shared__ short Bs[512][72];                  // 73728 B; reused as stage[64][544]
    short* stage = &Bs[0][0];
    int t = threadIdx.x;
    int lane = t & 63;
    int w = t >> 6;                                // 0..7 : col chunk
    size_t rowBase = (size_t)blockIdx.x * 128;
    int rsel = lane & 15, kq = lane >> 4;

    f32x4 acc[8][4];
    #pragma unroll
    for (int i = 0; i < 8; i++)
        #pragma unroll
        for (int j = 0; j < 4; j++)
            acc[i][j] = (f32x4){0.f, 0.f, 0.f, 0.f};

    for (int ks = 0; ks < 4; ++ks) {
        __syncthreads();
        #pragma unroll
        for (int j = 0; j < 2; ++j) {   // A: 128 rows x 8 chunks = 1024, 2 per thread
            int idx = t + j * 512;
            int row = idx >> 3, c8 = idx & 7;
            *(bh8*)&As[row][c8 * 8] =
                *(const bh8*)(act + (rowBase + row) * DD + ks * BK + c8 * 8);
        }
        #pragma unroll
        for (int j = 0; j < 8; ++j) {   // B: 512 rows x 8 chunks = 4096, 8 per thread
            int idx = t + j * 512;
            int row = idx >> 3, c8 = idx & 7;
            *(bh8*)&Bs[row][c8 * 8] =
                *(const bh8*)(Wct + (size_t)row * DD + ks * BK + c8 * 8);
        }
        __syncthreads();
        #pragma unroll
        for (int kk = 0; kk < BK; kk += 32) {
            bh8 af[8], bfr[4];
            int ksel = kk + kq * 8;
            #pragma unroll
            for (int mi = 0; mi < 8; mi++)
                af[mi] = *(const bh8*)&As[mi * 16 + rsel][ksel];
            #pragma unroll
            for (int ni = 0; ni < 4; ni++)
                bfr[ni] = *(const bh8*)&Bs[w * 64 + ni * 16 + rsel][ksel];
            #pragma unroll
            for (int mi = 0; mi < 8; mi++)
                #pragma unroll
                for (int ni = 0; ni < 4; ni++)
                    acc[mi][ni] = __builtin_amdgcn_mfma_f32_16x16x32_bf16(af[mi], bfr[ni], acc[mi][ni], 0, 0, 0);
        }
    }

    // epilogue: two 64-row half passes through LDS stage (pitch 544)
    #pragma unroll
    for (int h = 0; h < 2; ++h) {
        __syncthreads();                           // previous readers done
        #pragma unroll
        for (int ni = 0; ni < 4; ni++) {
            int col = w * 64 + ni * 16 + rsel;
            float bias = bc[col];
            #pragma unroll
            for (int mi = 0; mi < 4; mi++) {
                int r0 = mi * 16 + kq * 4;
                #pragma unroll
                for (int j = 0; j < 4; j++)
                    stage[(r0 + j) * 544 + col] = (short)f2bf(acc[h * 4 + mi][ni][j] + bias);
            }
        }
        __syncthreads();
        #pragma unroll
        for (int j = 0; j < 8; ++j) {   // 64 rows x 64 chunks(16B) = 4096, 8 per thread
            int idx = t + j * 512;
            int row = idx >> 6, c16 = idx & 63;
            size_t grow = rowBase + h * 64 + row;
            if (grow < NN)
                *(bh8*)(xlr + grow * 512 + c16 * 8) = *(const bh8*)&stage[row * 544 + c16 * 8];
        }
    }
}

// ---------------- aggregation: 1 wave/node, 4 ch/lane, no-max softmax, 2-way unroll ----------------
__global__ __launch_bounds__(256) void k_aggregate(const unsigned short* __restrict__ xlr,
                                                   const int* __restrict__ offsets,
                                                   const int* __restrict__ csr_src, const float* __restrict__ csr_feat,
                                                   const float* __restrict__ We, const float* __restrict__ att,
                                                   const float* __restrict__ bo,
                                                   unsigned short* __restrict__ act, float2* __restrict__ partial) {
    int lane = threadIdx.x & 63;
    int n = blockIdx.x * 4 + (threadIdx.x >> 6);
    int c0 = lane * 4;

    float4 attv = *(const float4*)(att + c0);
    float4 we3 = *(const float4*)(We + 3 * DD + c0);
    float4 w0v = *(const float4*)(We + 0 * DD + c0);
    float4 w1v = *(const float4*)(We + 1 * DD + c0);
    float4 w2v = *(const float4*)(We + 2 * DD + c0);

    uint2 xrr = *(const uint2*)(xlr + (size_t)n * 512 + 256 + c0);
    float xr0 = bf2f((unsigned short)(xrr.x & 0xffff));
    float xr1 = bf2f((unsigned short)(xrr.x >> 16));
    float xr2 = bf2f((unsigned short)(xrr.y & 0xffff));
    float xr3 = bf2f((unsigned short)(xrr.y >> 16));

    float b00 = xr0 + w0v.x, b01 = xr1 + w0v.y, b02 = xr2 + w0v.z, b03 = xr3 + w0v.w;
    float b10 = xr0 + w1v.x, b11 = xr1 + w1v.y, b12 = xr2 + w1v.z, b13 = xr3 + w1v.w;
    float b20 = xr0 + w2v.x, b21 = xr1 + w2v.y, b22 = xr2 + w2v.z, b23 = xr3 + w2v.w;

    int start = offsets[n], end = offsets[n + 1];
    float s = 0.f, a0 = 0.f, a1 = 0.f, a2 = 0.f, a3 = 0.f;
    int i = start;
    for (; i + 2 <= end; i += 2) {
        int pA = csr_src[i];     float fA = csr_feat[i];
        int pB = csr_src[i + 1]; float fB = csr_feat[i + 1];
        uint2 xvA = *(const uint2*)(xlr + (size_t)(pA & 0xFFFFF) * 512 + c0);
        uint2 xvB = *(const uint2*)(xlr + (size_t)(pB & 0xFFFFF) * 512 + c0);
        int tyA = pA >> 24, tyB = pB >> 24;
        float xA0 = bf2f((unsigned short)(xvA.x & 0xffff));
        float xA1 = bf2f((unsigned short)(xvA.x >> 16));
        float xA2 = bf2f((unsigned short)(xvA.y & 0xffff));
        float xA3 = bf2f((unsigned short)(xvA.y >> 16));
        float xB0 = bf2f((unsigned short)(xvB.x & 0xffff));
        float xB1 = bf2f((unsigned short)(xvB.x >> 16));
        float xB2 = bf2f((unsigned short)(xvB.y & 0xffff));
        float xB3 = bf2f((unsigned short)(xvB.y >> 16));
        float sA0 = (tyA == 0) ? b00 : (tyA == 1) ? b10 : b20;
        float sA1 = (tyA == 0) ? b01 : (tyA == 1) ? b11 : b21;
        float sA2 = (tyA == 0) ? b02 : (tyA == 1) ? b12 : b22;
        float sA3 = (tyA == 0) ? b03 : (tyA == 1) ? b13 : b23;
        float sB0 = (tyB == 0) ? b00 : (tyB == 1) ? b10 : b20;
        float sB1 = (tyB == 0) ? b01 : (tyB == 1) ? b11 : b21;
        float sB2 = (tyB == 0) ? b02 : (tyB == 1) ? b12 : b22;
        float sB3 = (tyB == 0) ? b03 : (tyB == 1) ? b13 : b23;
        float eA0 = xA0 + fmaf(fA, we3.x, sA0); eA0 = fmaxf(eA0, 0.2f * eA0);
        float eA1 = xA1 + fmaf(fA, we3.y, sA1); eA1 = fmaxf(eA1, 0.2f * eA1);
        float eA2 = xA2 + fmaf(fA, we3.z, sA2); eA2 = fmaxf(eA2, 0.2f * eA2);
        float eA3 = xA3 + fmaf(fA, we3.w, sA3); eA3 = fmaxf(eA3, 0.2f * eA3);
        float eB0 = xB0 + fmaf(fB, we3.x, sB0); eB0 = fmaxf(eB0, 0.2f * eB0);
        float eB1 = xB1 + fmaf(fB, we3.y, sB1); eB1 = fmaxf(eB1, 0.2f * eB1);
        float eB2 = xB2 + fmaf(fB, we3.z, sB2); eB2 = fmaxf(eB2, 0.2f * eB2);
        float eB3 = xB3 + fmaf(fB, we3.w, sB3); eB3 = fmaxf(eB3, 0.2f * eB3);
        float dA = attv.x * eA0 + attv.y * eA1 + attv.z * eA2 + attv.w * eA3;
        float dB = attv.x * eB0 + attv.y * eB1 + attv.z * eB2 + attv.w * eB3;
        dA += __shfl_xor(dA, 1, 64);  dB += __shfl_xor(dB, 1, 64);
        dA += __shfl_xor(dA, 2, 64);  dB += __shfl_xor(dB, 2, 64);
        dA += __shfl_xor(dA, 4, 64);  dB += __shfl_xor(dB, 4, 64);
        dA += __shfl_xor(dA, 8, 64);  dB += __shfl_xor(dB, 8, 64);
        float pa = __expf(fminf(fmaxf(dA, -60.f), 60.f));
        float pb = __expf(fminf(fmaxf(dB, -60.f), 60.f));
        s += pa + pb;
        a0 = fmaf(pa, xA0, fmaf(pb, xB0, a0));
        a1 = fmaf(pa, xA1, fmaf(pb, xB1, a1));
        a2 = fmaf(pa, xA2, fmaf(pb, xB2, a2));
        a3 = fmaf(pa, xA3, fmaf(pb, xB3, a3));
    }
    if (i < end) {
        int pA = csr_src[i]; float fA = csr_feat[i];
        uint2 xvA = *(const uint2*)(xlr + (size_t)(pA & 0xFFFFF) * 512 + c0);
        int tyA = pA >> 24;
        float xA0 = bf2f((unsigned short)(xvA.x & 0xffff));
        float xA1 = bf2f((unsigned short)(xvA.x >> 16));
        float xA2 = bf2f((unsigned short)(xvA.y & 0xffff));
        float xA3 = bf2f((unsigned short)(xvA.y >> 16));
        float sA0 = (tyA == 0) ? b00 : (tyA == 1) ? b10 : b20;
        float sA1 = (tyA == 0) ? b01 : (tyA == 1) ? b11 : b21;
        float sA2 = (tyA == 0) ? b02 : (tyA == 1) ? b12 : b22;
        float sA3 = (tyA == 0) ? b03 : (tyA == 1) ? b13 : b23;
        float eA0 = xA0 + fmaf(fA, we3.x, sA0); eA0 = fmaxf(eA0, 0.2f * eA0);
        float eA1 = xA1 + fmaf(fA, we3.y, sA1); eA1 = fmaxf(eA1, 0.2f * eA1);
        float eA2 = xA2 + fmaf(fA, we3.z, sA2); eA2 = fmaxf(eA2, 0.2f * eA2);
        float eA3 = xA3 + fmaf(fA, we3.w, sA3); eA3 = fmaxf(eA3, 0.2f * eA3);
        float dA = attv.x * eA0 + attv.y * eA1 + attv.z * eA2 + attv.w * eA3;
        dA += __shfl_xor(dA, 1, 64);
        dA += __shfl_xor(dA, 2, 64);
        dA += __shfl_xor(dA, 4, 64);
        dA += __shfl_xor(dA, 8, 64);
        float pa = __expf(fminf(fmaxf(dA, -60.f), 60.f));
        s += pa;
        a0 = fmaf(pa, xA0, a0);
        a1 = fmaf(pa, xA1, a1);
        a2 = fmaf(pa, xA2, a2);
        a3 = fmaf(pa, xA3, a3);
    }
    float inv = (end > start) ? __builtin_amdgcn_rcpf(s) : 0.f;
    float4 bov = *(const float4*)(bo + c0);
    float o0 = fmaxf(fmaf(a0, inv, bov.x), 0.f);
    float o1 = fmaxf(fmaf(a1, inv, bov.y), 0.f);
    float o2 = fmaxf(fmaf(a2, inv, bov.z), 0.f);
    float o3 = fmaxf(fmaf(a3, inv, bov.w), 0.f);
    uint2 pk;
    pk.x = (unsigned int)f2bf(o0) | ((unsigned int)f2bf(o1) << 16);
    pk.y = (unsigned int)f2bf(o2) | ((unsigned int)f2bf(o3) << 16);
    *(uint2*)(act + (size_t)n * DD + c0) = pk;

    float v1 = o0 + o1 + o2 + o3;
    float v2 = o0 * o0 + o1 * o1 + o2 * o2 + o3 * o3;
    #pragma unroll
    for (int off = 32; off > 0; off >>= 1) {
        v1 += __shfl_xor(v1, off, 64);
        v2 += __shfl_xor(v2, off, 64);
    }
    if (lane == 0) partial[n] = make_float2(v1, v2);
}

// ---------------- LN stats stage 1: 64-block partial reduce ----------------
__global__ __launch_bounds__(256) void k_lnreduce(const float2* __restrict__ partial,
                                                  double2* __restrict__ partial2) {
    int b = blockIdx.x, t = threadIdx.x;
    double s1 = 0.0, s2 = 0.0;
    for (int i = b * 256 + t; i < NN; i += 64 * 256) {
        float2 p = partial[i];
        s1 += p.x; s2 += p.y;
    }
    __shared__ double d1[256], d2[256];
    d1[t] = s1; d2[t] = s2;
    __syncthreads();
    for (int off = 128; off > 0; off >>= 1) {
        if (t < off) { d1[t] += d1[t + off]; d2[t] += d2[t + off]; }
        __syncthreads();
    }
    if (t == 0) partial2[b] = (double2){d1[0], d2[0]};
}

// ---------------- LN stats stage 2 ----------------
__global__ __launch_bounds__(256) void k_stats(const double2* __restrict__ partial2,
                                               const float* __restrict__ gamma, const float* __restrict__ beta,
                                               float* __restrict__ sc, float* __restrict__ vsh) {
    __shared__ double d1[64], d2[64];
    int t = threadIdx.x;
    if (t < 64) { double2 p = partial2[t]; d1[t] = p.x; d2[t] = p.y; }
    __syncthreads();
    for (int off = 32; off > 0; off >>= 1) {
        if (t < off) { d1[t] += d1[t + off]; d2[t] += d2[t + off]; }
        __syncthreads();
    }
    const double M = (double)NN * DD;
    double mu = d1[0] / M;
    double var = d2[0] / M - mu * mu;
    float rs = rsqrtf((float)(var + 1e-5));
    float scv = rs * gamma[t];
    sc[t] = scv;
    vsh[t] = beta[t] - (float)mu * scv;
}

// ---------------- fold LN into next layer's weights ----------------
__global__ __launch_bounds__(256) void k_foldw(const unsigned short* __restrict__ Wct,
                                               const float* __restrict__ bcL,
                                               const float* __restrict__ sc, const float* __restrict__ vsh,
                                               unsigned short* __restrict__ Wct2, float* __restrict__ bc2) {
    int row = (blockIdx.x << 2) + (threadIdx.x >> 6);  // 0..511
    int lane = threadIdx.x & 63;
    int k0 = lane * 4;
    uint2 raw = *(const uint2*)(Wct + (size_t)row * DD + k0);
    float w0 = bf2f((unsigned short)(raw.x & 0xffff));
    float w1 = bf2f((unsigned short)(raw.x >> 16));
    float w2 = bf2f((unsigned short)(raw.y & 0xffff));
    float w3 = bf2f((unsigned short)(raw.y >> 16));
    float4 scv = *(const float4*)(sc + k0);
    float4 vv  = *(const float4*)(vsh + k0);
    uint2 pk;
    pk.x = (unsigned int)f2bf(w0 * scv.x) | ((unsigned int)f2bf(w1 * scv.y) << 16);
    pk.y = (unsigned int)f2bf(w2 * scv.z) | ((unsigned int)f2bf(w3 * scv.w) << 16);
    *(uint2*)(Wct2 + (size_t)row * DD + k0) = pk;
    float d = w0 * vv.x + w1 * vv.y + w2 * vv.z + w3 * vv.w;
    #pragma unroll
    for (int off = 32; off > 0; off >>= 1) d += __shfl_xor(d, off, 64);
    if (lane == 0) bc2[row] = bcL[row] + d;
}

// ---------------- final output: h = act*sc + vsh (fp32) ----------------
__global__ __launch_bounds__(256) void k_final(const unsigned short* __restrict__ act,
                                               const float* __restrict__ sc, const float* __restrict__ vsh,
                                               float* __restrict__ h) {
    size_t i = ((size_t)blockIdx.x * 256 + threadIdx.x) * 4;
    uint2 raw = *(const uint2*)(act + i);
    int ch = (int)(i & (DD - 1));
    float4 scv = *(const float4*)(sc + ch);
    float4 vv  = *(const float4*)(vsh + ch);
    float4 o;
    o.x = fmaf(bf2f((unsigned short)(raw.x & 0xffff)), scv.x, vv.x);
    o.y = fmaf(bf2f((unsigned short)(raw.x >> 16)),    scv.y, vv.y);
    o.z = fmaf(bf2f((unsigned short)(raw.y & 0xffff)), scv.z, vv.z);
    o.w = fmaf(bf2f((unsigned short)(raw.y >> 16)),    scv.w, vv.w);
    *reinterpret_cast<float4*>(h + i) = o;
}

// ---------------- launch ----------------

extern "C" void kernel_launch(void* const* d_in, const int* in_sizes, int n_in,
                              void* d_out, int out_size, void* d_ws, size_t ws_size,
                              hipStream_t stream) {
    const float* x    = (const float*)d_in[0];
    const int*   ei   = (const int*)d_in[1];
    const int*   ety  = (const int*)d_in[2];
    const float* efe  = (const float*)d_in[3];
    const float* W0   = (const float*)d_in[4];
    const float* b0   = (const float*)d_in[5];
    const float* Wl   = (const float*)d_in[6];
    const float* bl   = (const float*)d_in[7];
    const float* Wr   = (const float*)d_in[8];
    const float* br   = (const float*)d_in[9];
    const float* We   = (const float*)d_in[10];
    const float* att  = (const float*)d_in[11];
    const float* bo   = (const float*)d_in[12];
    const float* gamma= (const float*)d_in[13];
    const float* beta = (const float*)d_in[14];
    float* h = (float*)d_out;

    char* base = (char*)d_ws;
    size_t off = 0;
    auto carve = [&](size_t bytes) -> void* {
        void* p = base + off;
        off += (bytes + 255) & ~(size_t)255;
        return p;
    };
    unsigned short* act  = (unsigned short*)carve((size_t)MPAD * DD * 2);
    unsigned short* xlr  = (unsigned short*)carve((size_t)NN * 512 * 2);
    unsigned short* Wct  = (unsigned short*)carve((size_t)LL * 512 * DD * 2);
    unsigned short* Wct2 = (unsigned short*)carve((size_t)512 * DD * 2);
    float* bc            = (float*)carve((size_t)LL * 512 * 4);
    float* bc2           = (float*)carve((size_t)512 * 4);
    float* sc            = (float*)carve((size_t)DD * 4);
    float* vsh           = (float*)carve((size_t)DD * 4);
    int*   deg      = (int*)carve((size_t)NN * 4);
    int*   offsets  = (int*)carve((size_t)(NN + 1) * 4);
    int*   bsum     = (int*)carve(1024);
    int*   boff     = (int*)carve(1024);
    int*   csr_src  = (int*)carve((size_t)EE * 4);
    float* csr_feat = (float*)carve((size_t)EE * 4);
    float2* partial = (float2*)carve((size_t)NN * 8);
    double2* partial2 = (double2*)carve((size_t)64 * 16);

    const int NB = (NN + SCAN_CHUNK - 1) / SCAN_CHUNK;

    // CSR build
    hipMemsetAsync(deg, 0, (size_t)NN * 4, stream);
    k_count<<<(EE + 255) / 256, 256, 0, stream>>>(ei + EE, deg, EE);
    k_scan1<<<NB, 256, 0, stream>>>(deg, bsum, NN);
    k_scan2<<<1, 64, 0, stream>>>(bsum, boff, NB, offsets, NN);
    k_scan3<<<NB, 256, 0, stream>>>(deg, boff, offsets, NN);
    hipMemsetAsync(deg, 0, (size_t)NN * 4, stream);
    k_fill<<<(EE + 255) / 256, 256, 0, stream>>>(ei, ei + EE, ety, efe, offsets, deg,
                                                 csr_src, csr_feat, EE);

    // weights -> bf16 B^T layout; bias concat
    k_cvtw<<<dim3(4, 4, 6), 256, 0, stream>>>(Wl, Wr, Wct);
    k_bias<<<6, 256, 0, stream>>>(bl, br, bc);

    // pre-encoder
    k_preenc<<<NN / 8, 256, 0, stream>>>(x, W0, b0, act);

    for (int l = 0; l < LL; l++) {
        const unsigned short* Wg = (l == 0) ? Wct : Wct2;
        const float* bg = (l == 0) ? bc : bc2;
        k_gemm<<<MPAD / 128, 512, 0, stream>>>(act, Wg, bg, xlr);
        k_aggregate<<<NN / 4, 256, 0, stream>>>(xlr, offsets, csr_src, csr_feat,
                                                We + (size_t)l * 4 * DD, att + (size_t)l * HH * CC,
                                                bo + (size_t)l * DD, act, partial);
        k_lnreduce<<<64, 256, 0, stream>>>(partial, partial2);
        k_stats<<<1, 256, 0, stream>>>(partial2, gamma, beta, sc, vsh);
        if (l < LL - 1)
            k_foldw<<<128, 256, 0, stream>>>(Wct + (size_t)(l + 1) * 512 * DD, bc + (size_t)(l + 1) * 512,
                                             sc, vsh, Wct2, bc2);
    }
    k_final<<<(NN * DD / 4) / 256, 256, 0, stream>>>(act, sc, vsh, h);
}

// Round 18
// 522.680 us; speedup vs baseline: 1.0596x; 1.0596x over previous
//
#include <hip/hip_runtime.h>
#include <hip/hip_bf16.h>

#define NN 100000
#define EE 300000
#define DD 256
#define HH 4
#define CC 64
#define LL 3
#define SCAN_CHUNK 1024

#define BM 64
#define BK 64
#define MPAD 100096   // 1564*64, padded row count for act

typedef __attribute__((ext_vector_type(8))) short bh8;    // 8 bf16 = 4 VGPR
typedef __attribute__((ext_vector_type(4))) float f32x4;

__device__ inline float bf2f(unsigned short u) {
    union { float f; unsigned int i; } c; c.i = ((unsigned int)u) << 16; return c.f;
}
__device__ inline unsigned short f2bf(float x) {
    __hip_bfloat16 b = __float2bfloat16(x);
    return *reinterpret_cast<unsigned short*>(&b);
}

// ---------------- CSR build ----------------

__global__ __launch_bounds__(256) void k_count(const int* __restrict__ dst, int* __restrict__ deg, int E_) {
    int e = blockIdx.x * 256 + threadIdx.x;
    if (e < E_) atomicAdd(&deg[dst[e]], 1);
}

__global__ __launch_bounds__(256) void k_scan1(const int* __restrict__ deg, int* __restrict__ bsum, int n) {
    int b = blockIdx.x;
    int base = b * SCAN_CHUNK;
    int t = threadIdx.x;
    int s = 0;
    for (int i = t; i < SCAN_CHUNK; i += 256) {
        int idx = base + i;
        if (idx < n) s += deg[idx];
    }
    __shared__ int sdata[256];
    sdata[t] = s;
    __syncthreads();
    for (int off = 128; off > 0; off >>= 1) {
        if (t < off) sdata[t] += sdata[t + off];
        __syncthreads();
    }
    if (t == 0) bsum[b] = sdata[0];
}

__global__ void k_scan2(const int* __restrict__ bsum, int* __restrict__ boff, int nb,
                        int* __restrict__ offsets, int n) {
    if (threadIdx.x == 0 && blockIdx.x == 0) {
        int run = 0;
        for (int i = 0; i < nb; i++) { boff[i] = run; run += bsum[i]; }
        offsets[n] = run;
    }
}

__global__ __launch_bounds__(256) void k_scan3(const int* __restrict__ deg, const int* __restrict__ boff,
                                               int* __restrict__ offsets, int n) {
    int b = blockIdx.x, t = threadIdx.x;
    int base = b * SCAN_CHUNK;
    int i0 = base + t * 4;
    int v[4]; int sum = 0;
    #pragma unroll
    for (int j = 0; j < 4; j++) {
        int idx = i0 + j;
        v[j] = (idx < n) ? deg[idx] : 0;
        sum += v[j];
    }
    __shared__ int sdata[256];
    sdata[t] = sum;
    __syncthreads();
    for (int off = 1; off < 256; off <<= 1) {
        int x = (t >= off) ? sdata[t - off] : 0;
        __syncthreads();
        sdata[t] += x;
        __syncthreads();
    }
    int excl = (t == 0) ? 0 : sdata[t - 1];
    int run = boff[b] + excl;
    #pragma unroll
    for (int j = 0; j < 4; j++) {
        int idx = i0 + j;
        if (idx < n) offsets[idx] = run;
        run += v[j];
    }
}

__global__ __launch_bounds__(256) void k_fill(const int* __restrict__ src, const int* __restrict__ dst,
                                              const int* __restrict__ ety, const float* __restrict__ efe,
                                              const int* __restrict__ offsets, int* __restrict__ cursor,
                                              int* __restrict__ csr_src, float* __restrict__ csr_feat, int E_) {
    int e = blockIdx.x * 256 + threadIdx.x;
    if (e < E_) {
        int d = dst[e];
        int pos = offsets[d] + atomicAdd(&cursor[d], 1);
        csr_src[pos] = src[e] | (ety[e] << 24);
        csr_feat[pos] = efe[e];
    }
}

// ---------------- weight prep: Wct[l][n][k] = W[l][k][n] as bf16 ----------------
__global__ __launch_bounds__(256) void k_cvtw(const float* __restrict__ Wl, const float* __restrict__ Wr,
                                              unsigned short* __restrict__ Wct) {
    int mat = blockIdx.z;
    int layer = mat >> 1, which = mat & 1;
    const float* src = (which ? Wr : Wl) + (size_t)layer * DD * DD;
    unsigned short* dst = Wct + (size_t)layer * 512 * DD + (size_t)which * DD * DD;
    int k0 = blockIdx.x * 64, n0 = blockIdx.y * 64;
    __shared__ float tile[64][65];
    int tx = threadIdx.x & 63, ty = threadIdx.x >> 6;
    #pragma unroll
    for (int i = 0; i < 16; i++) {
        int r = i * 4 + ty;
        tile[r][tx] = src[(size_t)(k0 + r) * DD + n0 + tx];
    }
    __syncthreads();
    #pragma unroll
    for (int i = 0; i < 16; i++) {
        int r = i * 4 + ty;
        dst[(size_t)(n0 + r) * DD + k0 + tx] = f2bf(tile[tx][r]);
    }
}

__global__ __launch_bounds__(256) void k_bias(const float* __restrict__ bl, const float* __restrict__ br,
                                              float* __restrict__ bc) {
    int i = blockIdx.x * 256 + threadIdx.x;
    if (i < LL * 512) {
        int l = i >> 9, j = i & 511;
        bc[i] = (j < 256) ? bl[l * DD + j] : br[l * DD + j - 256];
    }
}

// ---------------- pre-encoder: act = bf16(relu(x @ W0 + b0)) ----------------
__global__ __launch_bounds__(256) void k_preenc(const float* __restrict__ x, const float* __restrict__ W0,
                                                const float* __restrict__ b0, unsigned short* __restrict__ act) {
    __shared__ float xs[8][32];
    int t = threadIdx.x;
    int nb = blockIdx.x * 8;
    {
        int m = t >> 5, k = t & 31;
        xs[m][k] = x[(size_t)(nb + m) * 32 + k];
    }
    __syncthreads();
    float acc[8];
    float b = b0[t];
    #pragma unroll
    for (int m = 0; m < 8; m++) acc[m] = b;
    for (int k = 0; k < 32; k++) {
        float w = W0[k * DD + t];
        #pragma unroll
        for (int m = 0; m < 8; m++) acc[m] += xs[m][k] * w;
    }
    #pragma unroll
    for (int m = 0; m < 8; m++) {
        act[(size_t)(nb + m) * DD + t] = f2bf(fmaxf(acc[m], 0.f));
    }
}

// ---------------- MFMA GEMM (v2 champion, 71us measured): xlr[M,512] = act[M,256] @ Weff^T + beff ----------------
// BM=64 x full-N=512 per block (A read exactly once across the grid), 8 waves,
// wave w owns cols [w*64, w*64+64). LDS pitch 72 shorts. Epilogue stages the
// out tile in LDS (reusing Bs, pitch 544) and stores fully-coalesced 16B rows.
// Final structure after 8 measured variants (v2..v8: 71/78/76/188/76/86/80us):
// latency-structural at ~3.4x traffic floor; barrier removal, prefetch depth,
// gload_lds, and BM=128 (VGPR spill) all regressed or tied.
__global__ __launch_bounds__(512) void k_gemm(const unsigned short* __restrict__ act,
                                              const unsigned short* __restrict__ Wct,
                                              const float* __restrict__ bc,
                                              unsigned short* __restrict__ xlr) {
    __shared__ short As[BM][72];
    __shared__ short Bs[512][72];                  // reused as stage[64][544]
    short* stage = &Bs[0][0];
    int t = threadIdx.x;
    int lane = t & 63;
    int w = t >> 6;                                // 0..7 : col chunk
    size_t rowBase = (size_t)blockIdx.x * BM;
    int rsel = lane & 15, kq = lane >> 4;

    f32x4 acc[4][4];
    #pragma unroll
    for (int i = 0; i < 4; i++)
        #pragma unroll
        for (int j = 0; j < 4; j++)
            acc[i][j] = (f32x4){0.f, 0.f, 0.f, 0.f};

    for (int ks = 0; ks < 4; ++ks) {
        __syncthreads();
        {   // A: 64 rows x 8 chunks = 512 chunks, 1 per thread
            int row = t >> 3, c8 = t & 7;
            *(bh8*)&As[row][c8 * 8] =
                *(const bh8*)(act + (rowBase + row) * DD + ks * BK + c8 * 8);
        }
        #pragma unroll
        for (int j = 0; j < 8; ++j) {   // B: 512 rows x 8 chunks = 4096 chunks, 8 per thread
            int idx = t + j * 512;
            int row = idx >> 3, c8 = idx & 7;
            *(bh8*)&Bs[row][c8 * 8] =
                *(const bh8*)(Wct + (size_t)row * DD + ks * BK + c8 * 8);
        }
        __syncthreads();
        #pragma unroll
        for (int kk = 0; kk < BK; kk += 32) {
            bh8 af[4], bfr[4];
            int ksel = kk + kq * 8;
            #pragma unroll
            for (int mi = 0; mi < 4; mi++)
                af[mi] = *(const bh8*)&As[mi * 16 + rsel][ksel];
            #pragma unroll
            for (int ni = 0; ni < 4; ni++)
                bfr[ni] = *(const bh8*)&Bs[w * 64 + ni * 16 + rsel][ksel];
            #pragma unroll
            for (int mi = 0; mi < 4; mi++)
                #pragma unroll
                for (int ni = 0; ni < 4; ni++)
                    acc[mi][ni] = __builtin_amdgcn_mfma_f32_16x16x32_bf16(af[mi], bfr[ni], acc[mi][ni], 0, 0, 0);
        }
    }

    __syncthreads();
    #pragma unroll
    for (int ni = 0; ni < 4; ni++) {
        int col = w * 64 + ni * 16 + rsel;
        float bias = bc[col];
        #pragma unroll
        for (int mi = 0; mi < 4; mi++) {
            int r0 = mi * 16 + kq * 4;
            #pragma unroll
            for (int j = 0; j < 4; j++)
                stage[(r0 + j) * 544 + col] = (short)f2bf(acc[mi][ni][j] + bias);
        }
    }
    __syncthreads();
    #pragma unroll
    for (int j = 0; j < 8; ++j) {       // 64 rows x 64 chunks(16B) = 4096, 8 per thread
        int idx = t + j * 512;
        int row = idx >> 6, c16 = idx & 63;
        size_t grow = rowBase + row;
        if (grow < NN)
            *(bh8*)(xlr + grow * 512 + c16 * 8) = *(const bh8*)&stage[row * 544 + c16 * 8];
    }
}

// ---------------- aggregation: 1 wave/node, 4 ch/lane, no-max softmax, 2-way unroll ----------------
__global__ __launch_bounds__(256) void k_aggregate(const unsigned short* __restrict__ xlr,
                                                   const int* __restrict__ offsets,
                                                   const int* __restrict__ csr_src, const float* __restrict__ csr_feat,
                                                   const float* __restrict__ We, const float* __restrict__ att,
                                                   const float* __restrict__ bo,
                                                   unsigned short* __restrict__ act, float2* __restrict__ partial) {
    int lane = threadIdx.x & 63;
    int n = blockIdx.x * 4 + (threadIdx.x >> 6);
    int c0 = lane * 4;

    float4 attv = *(const float4*)(att + c0);
    float4 we3 = *(const float4*)(We + 3 * DD + c0);
    float4 w0v = *(const float4*)(We + 0 * DD + c0);
    float4 w1v = *(const float4*)(We + 1 * DD + c0);
    float4 w2v = *(const float4*)(We + 2 * DD + c0);

    uint2 xrr = *(const uint2*)(xlr + (size_t)n * 512 + 256 + c0);
    float xr0 = bf2f((unsigned short)(xrr.x & 0xffff));
    float xr1 = bf2f((unsigned short)(xrr.x >> 16));
    float xr2 = bf2f((unsigned short)(xrr.y & 0xffff));
    float xr3 = bf2f((unsigned short)(xrr.y >> 16));

    float b00 = xr0 + w0v.x, b01 = xr1 + w0v.y, b02 = xr2 + w0v.z, b03 = xr3 + w0v.w;
    float b10 = xr0 + w1v.x, b11 = xr1 + w1v.y, b12 = xr2 + w1v.z, b13 = xr3 + w1v.w;
    float b20 = xr0 + w2v.x, b21 = xr1 + w2v.y, b22 = xr2 + w2v.z, b23 = xr3 + w2v.w;

    int start = offsets[n], end = offsets[n + 1];
    float s = 0.f, a0 = 0.f, a1 = 0.f, a2 = 0.f, a3 = 0.f;
    int i = start;
    for (; i + 2 <= end; i += 2) {
        int pA = csr_src[i];     float fA = csr_feat[i];
        int pB = csr_src[i + 1]; float fB = csr_feat[i + 1];
        uint2 xvA = *(const uint2*)(xlr + (size_t)(pA & 0xFFFFF) * 512 + c0);
        uint2 xvB = *(const uint2*)(xlr + (size_t)(pB & 0xFFFFF) * 512 + c0);
        int tyA = pA >> 24, tyB = pB >> 24;
        float xA0 = bf2f((unsigned short)(xvA.x & 0xffff));
        float xA1 = bf2f((unsigned short)(xvA.x >> 16));
        float xA2 = bf2f((unsigned short)(xvA.y & 0xffff));
        float xA3 = bf2f((unsigned short)(xvA.y >> 16));
        float xB0 = bf2f((unsigned short)(xvB.x & 0xffff));
        float xB1 = bf2f((unsigned short)(xvB.x >> 16));
        float xB2 = bf2f((unsigned short)(xvB.y & 0xffff));
        float xB3 = bf2f((unsigned short)(xvB.y >> 16));
        float sA0 = (tyA == 0) ? b00 : (tyA == 1) ? b10 : b20;
        float sA1 = (tyA == 0) ? b01 : (tyA == 1) ? b11 : b21;
        float sA2 = (tyA == 0) ? b02 : (tyA == 1) ? b12 : b22;
        float sA3 = (tyA == 0) ? b03 : (tyA == 1) ? b13 : b23;
        float sB0 = (tyB == 0) ? b00 : (tyB == 1) ? b10 : b20;
        float sB1 = (tyB == 0) ? b01 : (tyB == 1) ? b11 : b21;
        float sB2 = (tyB == 0) ? b02 : (tyB == 1) ? b12 : b22;
        float sB3 = (tyB == 0) ? b03 : (tyB == 1) ? b13 : b23;
        float eA0 = xA0 + fmaf(fA, we3.x, sA0); eA0 = fmaxf(eA0, 0.2f * eA0);
        float eA1 = xA1 + fmaf(fA, we3.y, sA1); eA1 = fmaxf(eA1, 0.2f * eA1);
        float eA2 = xA2 + fmaf(fA, we3.z, sA2); eA2 = fmaxf(eA2, 0.2f * eA2);
        float eA3 = xA3 + fmaf(fA, we3.w, sA3); eA3 = fmaxf(eA3, 0.2f * eA3);
        float eB0 = xB0 + fmaf(fB, we3.x, sB0); eB0 = fmaxf(eB0, 0.2f * eB0);
        float eB1 = xB1 + fmaf(fB, we3.y, sB1); eB1 = fmaxf(eB1, 0.2f * eB1);
        float eB2 = xB2 + fmaf(fB, we3.z, sB2); eB2 = fmaxf(eB2, 0.2f * eB2);
        float eB3 = xB3 + fmaf(fB, we3.w, sB3); eB3 = fmaxf(eB3, 0.2f * eB3);
        float dA = attv.x * eA0 + attv.y * eA1 + attv.z * eA2 + attv.w * eA3;
        float dB = attv.x * eB0 + attv.y * eB1 + attv.z * eB2 + attv.w * eB3;
        dA += __shfl_xor(dA, 1, 64);  dB += __shfl_xor(dB, 1, 64);
        dA += __shfl_xor(dA, 2, 64);  dB += __shfl_xor(dB, 2, 64);
        dA += __shfl_xor(dA, 4, 64);  dB += __shfl_xor(dB, 4, 64);
        dA += __shfl_xor(dA, 8, 64);  dB += __shfl_xor(dB, 8, 64);
        float pa = __expf(fminf(fmaxf(dA, -60.f), 60.f));
        float pb = __expf(fminf(fmaxf(dB, -60.f), 60.f));
        s += pa + pb;
        a0 = fmaf(pa, xA0, fmaf(pb, xB0, a0));
        a1 = fmaf(pa, xA1, fmaf(pb, xB1, a1));
        a2 = fmaf(pa, xA2, fmaf(pb, xB2, a2));
        a3 = fmaf(pa, xA3, fmaf(pb, xB3, a3));
    }
    if (i < end) {
        int pA = csr_src[i]; float fA = csr_feat[i];
        uint2 xvA = *(const uint2*)(xlr + (size_t)(pA & 0xFFFFF) * 512 + c0);
        int tyA = pA >> 24;
        float xA0 = bf2f((unsigned short)(xvA.x & 0xffff));
        float xA1 = bf2f((unsigned short)(xvA.x >> 16));
        float xA2 = bf2f((unsigned short)(xvA.y & 0xffff));
        float xA3 = bf2f((unsigned short)(xvA.y >> 16));
        float sA0 = (tyA == 0) ? b00 : (tyA == 1) ? b10 : b20;
        float sA1 = (tyA == 0) ? b01 : (tyA == 1) ? b11 : b21;
        float sA2 = (tyA == 0) ? b02 : (tyA == 1) ? b12 : b22;
        float sA3 = (tyA == 0) ? b03 : (tyA == 1) ? b13 : b23;
        float eA0 = xA0 + fmaf(fA, we3.x, sA0); eA0 = fmaxf(eA0, 0.2f * eA0);
        float eA1 = xA1 + fmaf(fA, we3.y, sA1); eA1 = fmaxf(eA1, 0.2f * eA1);
        float eA2 = xA2 + fmaf(fA, we3.z, sA2); eA2 = fmaxf(eA2, 0.2f * eA2);
        float eA3 = xA3 + fmaf(fA, we3.w, sA3); eA3 = fmaxf(eA3, 0.2f * eA3);
        float dA = attv.x * eA0 + attv.y * eA1 + attv.z * eA2 + attv.w * eA3;
        dA += __shfl_xor(dA, 1, 64);
        dA += __shfl_xor(dA, 2, 64);
        dA += __shfl_xor(dA, 4, 64);
        dA += __shfl_xor(dA, 8, 64);
        float pa = __expf(fminf(fmaxf(dA, -60.f), 60.f));
        s += pa;
        a0 = fmaf(pa, xA0, a0);
        a1 = fmaf(pa, xA1, a1);
        a2 = fmaf(pa, xA2, a2);
        a3 = fmaf(pa, xA3, a3);
    }
    float inv = (end > start) ? __builtin_amdgcn_rcpf(s) : 0.f;
    float4 bov = *(const float4*)(bo + c0);
    float o0 = fmaxf(fmaf(a0, inv, bov.x), 0.f);
    float o1 = fmaxf(fmaf(a1, inv, bov.y), 0.f);
    float o2 = fmaxf(fmaf(a2, inv, bov.z), 0.f);
    float o3 = fmaxf(fmaf(a3, inv, bov.w), 0.f);
    uint2 pk;
    pk.x = (unsigned int)f2bf(o0) | ((unsigned int)f2bf(o1) << 16);
    pk.y = (unsigned int)f2bf(o2) | ((unsigned int)f2bf(o3) << 16);
    *(uint2*)(act + (size_t)n * DD + c0) = pk;

    float v1 = o0 + o1 + o2 + o3;
    float v2 = o0 * o0 + o1 * o1 + o2 * o2 + o3 * o3;
    #pragma unroll
    for (int off = 32; off > 0; off >>= 1) {
        v1 += __shfl_xor(v1, off, 64);
        v2 += __shfl_xor(v2, off, 64);
    }
    if (lane == 0) partial[n] = make_float2(v1, v2);
}

// ---------------- LN stats stage 1: 64-block partial reduce ----------------
__global__ __launch_bounds__(256) void k_lnreduce(const float2* __restrict__ partial,
                                                  double2* __restrict__ partial2) {
    int b = blockIdx.x, t = threadIdx.x;
    double s1 = 0.0, s2 = 0.0;
    for (int i = b * 256 + t; i < NN; i += 64 * 256) {
        float2 p = partial[i];
        s1 += p.x; s2 += p.y;
    }
    __shared__ double d1[256], d2[256];
    d1[t] = s1; d2[t] = s2;
    __syncthreads();
    for (int off = 128; off > 0; off >>= 1) {
        if (t < off) { d1[t] += d1[t + off]; d2[t] += d2[t + off]; }
        __syncthreads();
    }
    if (t == 0) partial2[b] = (double2){d1[0], d2[0]};
}

// ---------------- LN stats stage 2 ----------------
__global__ __launch_bounds__(256) void k_stats(const double2* __restrict__ partial2,
                                               const float* __restrict__ gamma, const float* __restrict__ beta,
                                               float* __restrict__ sc, float* __restrict__ vsh) {
    __shared__ double d1[64], d2[64];
    int t = threadIdx.x;
    if (t < 64) { double2 p = partial2[t]; d1[t] = p.x; d2[t] = p.y; }
    __syncthreads();
    for (int off = 32; off > 0; off >>= 1) {
        if (t < off) { d1[t] += d1[t + off]; d2[t] += d2[t + off]; }
        __syncthreads();
    }
    const double M = (double)NN * DD;
    double mu = d1[0] / M;
    double var = d2[0] / M - mu * mu;
    float rs = rsqrtf((float)(var + 1e-5));
    float scv = rs * gamma[t];
    sc[t] = scv;
    vsh[t] = beta[t] - (float)mu * scv;
}

// ---------------- fold LN into next layer's weights ----------------
__global__ __launch_bounds__(256) void k_foldw(const unsigned short* __restrict__ Wct,
                                               const float* __restrict__ bcL,
                                               const float* __restrict__ sc, const float* __restrict__ vsh,
                                               unsigned short* __restrict__ Wct2, float* __restrict__ bc2) {
    int row = (blockIdx.x << 2) + (threadIdx.x >> 6);  // 0..511
    int lane = threadIdx.x & 63;
    int k0 = lane * 4;
    uint2 raw = *(const uint2*)(Wct + (size_t)row * DD + k0);
    float w0 = bf2f((unsigned short)(raw.x & 0xffff));
    float w1 = bf2f((unsigned short)(raw.x >> 16));
    float w2 = bf2f((unsigned short)(raw.y & 0xffff));
    float w3 = bf2f((unsigned short)(raw.y >> 16));
    float4 scv = *(const float4*)(sc + k0);
    float4 vv  = *(const float4*)(vsh + k0);
    uint2 pk;
    pk.x = (unsigned int)f2bf(w0 * scv.x) | ((unsigned int)f2bf(w1 * scv.y) << 16);
    pk.y = (unsigned int)f2bf(w2 * scv.z) | ((unsigned int)f2bf(w3 * scv.w) << 16);
    *(uint2*)(Wct2 + (size_t)row * DD + k0) = pk;
    float d = w0 * vv.x + w1 * vv.y + w2 * vv.z + w3 * vv.w;
    #pragma unroll
    for (int off = 32; off > 0; off >>= 1) d += __shfl_xor(d, off, 64);
    if (lane == 0) bc2[row] = bcL[row] + d;
}

// ---------------- final output: h = act*sc + vsh (fp32) ----------------
__global__ __launch_bounds__(256) void k_final(const unsigned short* __restrict__ act,
                                               const float* __restrict__ sc, const float* __restrict__ vsh,
                                               float* __restrict__ h) {
    size_t i = ((size_t)blockIdx.x * 256 + threadIdx.x) * 4;
    uint2 raw = *(const uint2*)(act + i);
    int ch = (int)(i & (DD - 1));
    float4 scv = *(const float4*)(sc + ch);
    float4 vv  = *(const float4*)(vsh + ch);
    float4 o;
    o.x = fmaf(bf2f((unsigned short)(raw.x & 0xffff)), scv.x, vv.x);
    o.y = fmaf(bf2f((unsigned short)(raw.x >> 16)),    scv.y, vv.y);
    o.z = fmaf(bf2f((unsigned short)(raw.y & 0xffff)), scv.z, vv.z);
    o.w = fmaf(bf2f((unsigned short)(raw.y >> 16)),    scv.w, vv.w);
    *reinterpret_cast<float4*>(h + i) = o;
}

// ---------------- launch ----------------

extern "C" void kernel_launch(void* const* d_in, const int* in_sizes, int n_in,
                              void* d_out, int out_size, void* d_ws, size_t ws_size,
                              hipStream_t stream) {
    const float* x    = (const float*)d_in[0];
    const int*   ei   = (const int*)d_in[1];
    const int*   ety  = (const int*)d_in[2];
    const float* efe  = (const float*)d_in[3];
    const float* W0   = (const float*)d_in[4];
    const float* b0   = (const float*)d_in[5];
    const float* Wl   = (const float*)d_in[6];
    const float* bl   = (const float*)d_in[7];
    const float* Wr   = (const float*)d_in[8];
    const float* br   = (const float*)d_in[9];
    const float* We   = (const float*)d_in[10];
    const float* att  = (const float*)d_in[11];
    const float* bo   = (const float*)d_in[12];
    const float* gamma= (const float*)d_in[13];
    const float* beta = (const float*)d_in[14];
    float* h = (float*)d_out;

    char* base = (char*)d_ws;
    size_t off = 0;
    auto carve = [&](size_t bytes) -> void* {
        void* p = base + off;
        off += (bytes + 255) & ~(size_t)255;
        return p;
    };
    unsigned short* act  = (unsigned short*)carve((size_t)MPAD * DD * 2);
    unsigned short* xlr  = (unsigned short*)carve((size_t)NN * 512 * 2);
    unsigned short* Wct  = (unsigned short*)carve((size_t)LL * 512 * DD * 2);
    unsigned short* Wct2 = (unsigned short*)carve((size_t)512 * DD * 2);
    float* bc            = (float*)carve((size_t)LL * 512 * 4);
    float* bc2           = (float*)carve((size_t)512 * 4);
    float* sc            = (float*)carve((size_t)DD * 4);
    float* vsh           = (float*)carve((size_t)DD * 4);
    int*   deg      = (int*)carve((size_t)NN * 4);
    int*   offsets  = (int*)carve((size_t)(NN + 1) * 4);
    int*   bsum     = (int*)carve(1024);
    int*   boff     = (int*)carve(1024);
    int*   csr_src  = (int*)carve((size_t)EE * 4);
    float* csr_feat = (float*)carve((size_t)EE * 4);
    float2* partial = (float2*)carve((size_t)NN * 8);
    double2* partial2 = (double2*)carve((size_t)64 * 16);

    const int NB = (NN + SCAN_CHUNK - 1) / SCAN_CHUNK;

    // CSR build
    hipMemsetAsync(deg, 0, (size_t)NN * 4, stream);
    k_count<<<(EE + 255) / 256, 256, 0, stream>>>(ei + EE, deg, EE);
    k_scan1<<<NB, 256, 0, stream>>>(deg, bsum, NN);
    k_scan2<<<1, 64, 0, stream>>>(bsum, boff, NB, offsets, NN);
    k_scan3<<<NB, 256, 0, stream>>>(deg, boff, offsets, NN);
    hipMemsetAsync(deg, 0, (size_t)NN * 4, stream);
    k_fill<<<(EE + 255) / 256, 256, 0, stream>>>(ei, ei + EE, ety, efe, offsets, deg,
                                                 csr_src, csr_feat, EE);

    // weights -> bf16 B^T layout; bias concat
    k_cvtw<<<dim3(4, 4, 6), 256, 0, stream>>>(Wl, Wr, Wct);
    k_bias<<<6, 256, 0, stream>>>(bl, br, bc);

    // pre-encoder
    k_preenc<<<NN / 8, 256, 0, stream>>>(x, W0, b0, act);

    for (int l = 0; l < LL; l++) {
        const unsigned short* Wg = (l == 0) ? Wct : Wct2;
        const float* bg = (l == 0) ? bc : bc2;
        k_gemm<<<MPAD / 64, 512, 0, stream>>>(act, Wg, bg, xlr);
        k_aggregate<<<NN / 4, 256, 0, stream>>>(xlr, offsets, csr_src, csr_feat,
                                                We + (size_t)l * 4 * DD, att + (size_t)l * HH * CC,
                                                bo + (size_t)l * DD, act, partial);
        k_lnreduce<<<64, 256, 0, stream>>>(partial, partial2);
        k_stats<<<1, 256, 0, stream>>>(partial2, gamma, beta, sc, vsh);
        if (l < LL - 1)
            k_foldw<<<128, 256, 0, stream>>>(Wct + (size_t)(l + 1) * 512 * DD, bc + (size_t)(l + 1) * 512,
                                             sc, vsh, Wct2, bc2);
    }
    k_final<<<(NN * DD / 4) / 256, 256, 0, stream>>>(act, sc, vsh, h);
}

// Round 19
// 514.660 us; speedup vs baseline: 1.0761x; 1.0156x over previous
//
#include <hip/hip_runtime.h>
#include <hip/hip_bf16.h>

#define NN 100000
#define EE 300000
#define DD 256
#define HH 4
#define CC 64
#define LL 3
#define SCAN_CHUNK 1024

#define BM 64
#define BK 128
#define MPAD 100096   // 1564*64, padded row count for act

typedef __attribute__((ext_vector_type(8))) short bh8;    // 8 bf16 = 4 VGPR
typedef __attribute__((ext_vector_type(4))) float f32x4;

__device__ inline float bf2f(unsigned short u) {
    union { float f; unsigned int i; } c; c.i = ((unsigned int)u) << 16; return c.f;
}
__device__ inline unsigned short f2bf(float x) {
    __hip_bfloat16 b = __float2bfloat16(x);
    return *reinterpret_cast<unsigned short*>(&b);
}

// ---------------- CSR build ----------------

__global__ __launch_bounds__(256) void k_count(const int* __restrict__ dst, int* __restrict__ deg, int E_) {
    int e = blockIdx.x * 256 + threadIdx.x;
    if (e < E_) atomicAdd(&deg[dst[e]], 1);
}

__global__ __launch_bounds__(256) void k_scan1(const int* __restrict__ deg, int* __restrict__ bsum, int n) {
    int b = blockIdx.x;
    int base = b * SCAN_CHUNK;
    int t = threadIdx.x;
    int s = 0;
    for (int i = t; i < SCAN_CHUNK; i += 256) {
        int idx = base + i;
        if (idx < n) s += deg[idx];
    }
    __shared__ int sdata[256];
    sdata[t] = s;
    __syncthreads();
    for (int off = 128; off > 0; off >>= 1) {
        if (t < off) sdata[t] += sdata[t + off];
        __syncthreads();
    }
    if (t == 0) bsum[b] = sdata[0];
}

__global__ void k_scan2(const int* __restrict__ bsum, int* __restrict__ boff, int nb,
                        int* __restrict__ offsets, int n) {
    if (threadIdx.x == 0 && blockIdx.x == 0) {
        int run = 0;
        for (int i = 0; i < nb; i++) { boff[i] = run; run += bsum[i]; }
        offsets[n] = run;
    }
}

__global__ __launch_bounds__(256) void k_scan3(const int* __restrict__ deg, const int* __restrict__ boff,
                                               int* __restrict__ offsets, int n) {
    int b = blockIdx.x, t = threadIdx.x;
    int base = b * SCAN_CHUNK;
    int i0 = base + t * 4;
    int v[4]; int sum = 0;
    #pragma unroll
    for (int j = 0; j < 4; j++) {
        int idx = i0 + j;
        v[j] = (idx < n) ? deg[idx] : 0;
        sum += v[j];
    }
    __shared__ int sdata[256];
    sdata[t] = sum;
    __syncthreads();
    for (int off = 1; off < 256; off <<= 1) {
        int x = (t >= off) ? sdata[t - off] : 0;
        __syncthreads();
        sdata[t] += x;
        __syncthreads();
    }
    int excl = (t == 0) ? 0 : sdata[t - 1];
    int run = boff[b] + excl;
    #pragma unroll
    for (int j = 0; j < 4; j++) {
        int idx = i0 + j;
        if (idx < n) offsets[idx] = run;
        run += v[j];
    }
}

__global__ __launch_bounds__(256) void k_fill(const int* __restrict__ src, const int* __restrict__ dst,
                                              const int* __restrict__ ety, const float* __restrict__ efe,
                                              const int* __restrict__ offsets, int* __restrict__ cursor,
                                              int* __restrict__ csr_src, float* __restrict__ csr_feat, int E_) {
    int e = blockIdx.x * 256 + threadIdx.x;
    if (e < E_) {
        int d = dst[e];
        int pos = offsets[d] + atomicAdd(&cursor[d], 1);
        csr_src[pos] = src[e] | (ety[e] << 24);
        csr_feat[pos] = efe[e];
    }
}

// ---------------- weight prep: Wct[l][n][k] = W[l][k][n] as bf16 ----------------
__global__ __launch_bounds__(256) void k_cvtw(const float* __restrict__ Wl, const float* __restrict__ Wr,
                                              unsigned short* __restrict__ Wct) {
    int mat = blockIdx.z;
    int layer = mat >> 1, which = mat & 1;
    const float* src = (which ? Wr : Wl) + (size_t)layer * DD * DD;
    unsigned short* dst = Wct + (size_t)layer * 512 * DD + (size_t)which * DD * DD;
    int k0 = blockIdx.x * 64, n0 = blockIdx.y * 64;
    __shared__ float tile[64][65];
    int tx = threadIdx.x & 63, ty = threadIdx.x >> 6;
    #pragma unroll
    for (int i = 0; i < 16; i++) {
        int r = i * 4 + ty;
        tile[r][tx] = src[(size_t)(k0 + r) * DD + n0 + tx];
    }
    __syncthreads();
    #pragma unroll
    for (int i = 0; i < 16; i++) {
        int r = i * 4 + ty;
        dst[(size_t)(n0 + r) * DD + k0 + tx] = f2bf(tile[tx][r]);
    }
}

__global__ __launch_bounds__(256) void k_bias(const float* __restrict__ bl, const float* __restrict__ br,
                                              float* __restrict__ bc) {
    int i = blockIdx.x * 256 + threadIdx.x;
    if (i < LL * 512) {
        int l = i >> 9, j = i & 511;
        bc[i] = (j < 256) ? bl[l * DD + j] : br[l * DD + j - 256];
    }
}

// ---------------- pre-encoder: act = bf16(relu(x @ W0 + b0)) ----------------
__global__ __launch_bounds__(256) void k_preenc(const float* __restrict__ x, const float* __restrict__ W0,
                                                const float* __restrict__ b0, unsigned short* __restrict__ act) {
    __shared__ float xs[8][32];
    int t = threadIdx.x;
    int nb = blockIdx.x * 8;
    {
        int m = t >> 5, k = t & 31;
        xs[m][k] = x[(size_t)(nb + m) * 32 + k];
    }
    __syncthreads();
    float acc[8];
    float b = b0[t];
    #pragma unroll
    for (int m = 0; m < 8; m++) acc[m] = b;
    for (int k = 0; k < 32; k++) {
        float w = W0[k * DD + t];
        #pragma unroll
        for (int m = 0; m < 8; m++) acc[m] += xs[m][k] * w;
    }
    #pragma unroll
    for (int m = 0; m < 8; m++) {
        act[(size_t)(nb + m) * DD + t] = f2bf(fmaxf(acc[m], 0.f));
    }
}

// ---------------- MFMA GEMM v9: xlr[M,512] = act[M,256] @ Weff^T + beff ----------------
// Champion v2 structure with BK=128: 2 k-phases instead of 4. Each barrier
// drains vmcnt(0) and exposes ~940cy of memory latency to all waves (measured
// via v5: +8 convoys/block = +117us); halving phase count removes 2 convoys.
// LDS = As[64][136] + Bs[512][136] = 156.7KB (fits 160KB pool; 1 blk/CU,
// shown costless). Pitch 136 shorts === 4 mod 32 dw = same bank geometry as
// the 71us champion. MFMA total unchanged (128/block). Epilogue unchanged.
__global__ __launch_bounds__(512) void k_gemm(const unsigned short* __restrict__ act,
                                              const unsigned short* __restrict__ Wct,
                                              const float* __restrict__ bc,
                                              unsigned short* __restrict__ xlr) {
    __shared__ short As[BM][136];                  // 17408 B
    __shared__ short Bs[512][136];                 // 139264 B; reused as stage[64][544]
    short* stage = &Bs[0][0];
    int t = threadIdx.x;
    int lane = t & 63;
    int w = t >> 6;                                // 0..7 : col chunk
    size_t rowBase = (size_t)blockIdx.x * BM;
    int rsel = lane & 15, kq = lane >> 4;

    f32x4 acc[4][4];
    #pragma unroll
    for (int i = 0; i < 4; i++)
        #pragma unroll
        for (int j = 0; j < 4; j++)
            acc[i][j] = (f32x4){0.f, 0.f, 0.f, 0.f};

    for (int ks = 0; ks < 2; ++ks) {
        __syncthreads();
        #pragma unroll
        for (int j = 0; j < 2; ++j) {   // A: 64 rows x 16 chunks = 1024 chunks, 2/thread
            int idx = t + j * 512;
            int row = idx >> 4, c16 = idx & 15;
            *(bh8*)&As[row][c16 * 8] =
                *(const bh8*)(act + (rowBase + row) * DD + ks * BK + c16 * 8);
        }
        #pragma unroll
        for (int j = 0; j < 16; ++j) {  // B: 512 rows x 16 chunks = 8192 chunks, 16/thread
            int idx = t + j * 512;
            int row = idx >> 4, c16 = idx & 15;
            *(bh8*)&Bs[row][c16 * 8] =
                *(const bh8*)(Wct + (size_t)row * DD + ks * BK + c16 * 8);
        }
        __syncthreads();
        #pragma unroll
        for (int kk = 0; kk < BK; kk += 32) {
            bh8 af[4], bfr[4];
            int ksel = kk + kq * 8;
            #pragma unroll
            for (int mi = 0; mi < 4; mi++)
                af[mi] = *(const bh8*)&As[mi * 16 + rsel][ksel];
            #pragma unroll
            for (int ni = 0; ni < 4; ni++)
                bfr[ni] = *(const bh8*)&Bs[w * 64 + ni * 16 + rsel][ksel];
            #pragma unroll
            for (int mi = 0; mi < 4; mi++)
                #pragma unroll
                for (int ni = 0; ni < 4; ni++)
                    acc[mi][ni] = __builtin_amdgcn_mfma_f32_16x16x32_bf16(af[mi], bfr[ni], acc[mi][ni], 0, 0, 0);
        }
    }

    __syncthreads();
    #pragma unroll
    for (int ni = 0; ni < 4; ni++) {
        int col = w * 64 + ni * 16 + rsel;
        float bias = bc[col];
        #pragma unroll
        for (int mi = 0; mi < 4; mi++) {
            int r0 = mi * 16 + kq * 4;
            #pragma unroll
            for (int j = 0; j < 4; j++)
                stage[(r0 + j) * 544 + col] = (short)f2bf(acc[mi][ni][j] + bias);
        }
    }
    __syncthreads();
    #pragma unroll
    for (int j = 0; j < 8; ++j) {       // 64 rows x 64 chunks(16B) = 4096, 8 per thread
        int idx = t + j * 512;
        int row = idx >> 6, c16 = idx & 63;
        size_t grow = rowBase + row;
        if (grow < NN)
            *(bh8*)(xlr + grow * 512 + c16 * 8) = *(const bh8*)&stage[row * 544 + c16 * 8];
    }
}

// ---------------- aggregation: 1 wave/node, 4 ch/lane, no-max softmax, 2-way unroll ----------------
__global__ __launch_bounds__(256) void k_aggregate(const unsigned short* __restrict__ xlr,
                                                   const int* __restrict__ offsets,
                                                   const int* __restrict__ csr_src, const float* __restrict__ csr_feat,
                                                   const float* __restrict__ We, const float* __restrict__ att,
                                                   const float* __restrict__ bo,
                                                   unsigned short* __restrict__ act, float2* __restrict__ partial) {
    int lane = threadIdx.x & 63;
    int n = blockIdx.x * 4 + (threadIdx.x >> 6);
    int c0 = lane * 4;

    float4 attv = *(const float4*)(att + c0);
    float4 we3 = *(const float4*)(We + 3 * DD + c0);
    float4 w0v = *(const float4*)(We + 0 * DD + c0);
    float4 w1v = *(const float4*)(We + 1 * DD + c0);
    float4 w2v = *(const float4*)(We + 2 * DD + c0);

    uint2 xrr = *(const uint2*)(xlr + (size_t)n * 512 + 256 + c0);
    float xr0 = bf2f((unsigned short)(xrr.x & 0xffff));
    float xr1 = bf2f((unsigned short)(xrr.x >> 16));
    float xr2 = bf2f((unsigned short)(xrr.y & 0xffff));
    float xr3 = bf2f((unsigned short)(xrr.y >> 16));

    float b00 = xr0 + w0v.x, b01 = xr1 + w0v.y, b02 = xr2 + w0v.z, b03 = xr3 + w0v.w;
    float b10 = xr0 + w1v.x, b11 = xr1 + w1v.y, b12 = xr2 + w1v.z, b13 = xr3 + w1v.w;
    float b20 = xr0 + w2v.x, b21 = xr1 + w2v.y, b22 = xr2 + w2v.z, b23 = xr3 + w2v.w;

    int start = offsets[n], end = offsets[n + 1];
    float s = 0.f, a0 = 0.f, a1 = 0.f, a2 = 0.f, a3 = 0.f;
    int i = start;
    for (; i + 2 <= end; i += 2) {
        int pA = csr_src[i];     float fA = csr_feat[i];
        int pB = csr_src[i + 1]; float fB = csr_feat[i + 1];
        uint2 xvA = *(const uint2*)(xlr + (size_t)(pA & 0xFFFFF) * 512 + c0);
        uint2 xvB = *(const uint2*)(xlr + (size_t)(pB & 0xFFFFF) * 512 + c0);
        int tyA = pA >> 24, tyB = pB >> 24;
        float xA0 = bf2f((unsigned short)(xvA.x & 0xffff));
        float xA1 = bf2f((unsigned short)(xvA.x >> 16));
        float xA2 = bf2f((unsigned short)(xvA.y & 0xffff));
        float xA3 = bf2f((unsigned short)(xvA.y >> 16));
        float xB0 = bf2f((unsigned short)(xvB.x & 0xffff));
        float xB1 = bf2f((unsigned short)(xvB.x >> 16));
        float xB2 = bf2f((unsigned short)(xvB.y & 0xffff));
        float xB3 = bf2f((unsigned short)(xvB.y >> 16));
        float sA0 = (tyA == 0) ? b00 : (tyA == 1) ? b10 : b20;
        float sA1 = (tyA == 0) ? b01 : (tyA == 1) ? b11 : b21;
        float sA2 = (tyA == 0) ? b02 : (tyA == 1) ? b12 : b22;
        float sA3 = (tyA == 0) ? b03 : (tyA == 1) ? b13 : b23;
        float sB0 = (tyB == 0) ? b00 : (tyB == 1) ? b10 : b20;
        float sB1 = (tyB == 0) ? b01 : (tyB == 1) ? b11 : b21;
        float sB2 = (tyB == 0) ? b02 : (tyB == 1) ? b12 : b22;
        float sB3 = (tyB == 0) ? b03 : (tyB == 1) ? b13 : b23;
        float eA0 = xA0 + fmaf(fA, we3.x, sA0); eA0 = fmaxf(eA0, 0.2f * eA0);
        float eA1 = xA1 + fmaf(fA, we3.y, sA1); eA1 = fmaxf(eA1, 0.2f * eA1);
        float eA2 = xA2 + fmaf(fA, we3.z, sA2); eA2 = fmaxf(eA2, 0.2f * eA2);
        float eA3 = xA3 + fmaf(fA, we3.w, sA3); eA3 = fmaxf(eA3, 0.2f * eA3);
        float eB0 = xB0 + fmaf(fB, we3.x, sB0); eB0 = fmaxf(eB0, 0.2f * eB0);
        float eB1 = xB1 + fmaf(fB, we3.y, sB1); eB1 = fmaxf(eB1, 0.2f * eB1);
        float eB2 = xB2 + fmaf(fB, we3.z, sB2); eB2 = fmaxf(eB2, 0.2f * eB2);
        float eB3 = xB3 + fmaf(fB, we3.w, sB3); eB3 = fmaxf(eB3, 0.2f * eB3);
        float dA = attv.x * eA0 + attv.y * eA1 + attv.z * eA2 + attv.w * eA3;
        float dB = attv.x * eB0 + attv.y * eB1 + attv.z * eB2 + attv.w * eB3;
        dA += __shfl_xor(dA, 1, 64);  dB += __shfl_xor(dB, 1, 64);
        dA += __shfl_xor(dA, 2, 64);  dB += __shfl_xor(dB, 2, 64);
        dA += __shfl_xor(dA, 4, 64);  dB += __shfl_xor(dB, 4, 64);
        dA += __shfl_xor(dA, 8, 64);  dB += __shfl_xor(dB, 8, 64);
        float pa = __expf(fminf(fmaxf(dA, -60.f), 60.f));
        float pb = __expf(fminf(fmaxf(dB, -60.f), 60.f));
        s += pa + pb;
        a0 = fmaf(pa, xA0, fmaf(pb, xB0, a0));
        a1 = fmaf(pa, xA1, fmaf(pb, xB1, a1));
        a2 = fmaf(pa, xA2, fmaf(pb, xB2, a2));
        a3 = fmaf(pa, xA3, fmaf(pb, xB3, a3));
    }
    if (i < end) {
        int pA = csr_src[i]; float fA = csr_feat[i];
        uint2 xvA = *(const uint2*)(xlr + (size_t)(pA & 0xFFFFF) * 512 + c0);
        int tyA = pA >> 24;
        float xA0 = bf2f((unsigned short)(xvA.x & 0xffff));
        float xA1 = bf2f((unsigned short)(xvA.x >> 16));
        float xA2 = bf2f((unsigned short)(xvA.y & 0xffff));
        float xA3 = bf2f((unsigned short)(xvA.y >> 16));
        float sA0 = (tyA == 0) ? b00 : (tyA == 1) ? b10 : b20;
        float sA1 = (tyA == 0) ? b01 : (tyA == 1) ? b11 : b21;
        float sA2 = (tyA == 0) ? b02 : (tyA == 1) ? b12 : b22;
        float sA3 = (tyA == 0) ? b03 : (tyA == 1) ? b13 : b23;
        float eA0 = xA0 + fmaf(fA, we3.x, sA0); eA0 = fmaxf(eA0, 0.2f * eA0);
        float eA1 = xA1 + fmaf(fA, we3.y, sA1); eA1 = fmaxf(eA1, 0.2f * eA1);
        float eA2 = xA2 + fmaf(fA, we3.z, sA2); eA2 = fmaxf(eA2, 0.2f * eA2);
        float eA3 = xA3 + fmaf(fA, we3.w, sA3); eA3 = fmaxf(eA3, 0.2f * eA3);
        float dA = attv.x * eA0 + attv.y * eA1 + attv.z * eA2 + attv.w * eA3;
        dA += __shfl_xor(dA, 1, 64);
        dA += __shfl_xor(dA, 2, 64);
        dA += __shfl_xor(dA, 4, 64);
        dA += __shfl_xor(dA, 8, 64);
        float pa = __expf(fminf(fmaxf(dA, -60.f), 60.f));
        s += pa;
        a0 = fmaf(pa, xA0, a0);
        a1 = fmaf(pa, xA1, a1);
        a2 = fmaf(pa, xA2, a2);
        a3 = fmaf(pa, xA3, a3);
    }
    float inv = (end > start) ? __builtin_amdgcn_rcpf(s) : 0.f;
    float4 bov = *(const float4*)(bo + c0);
    float o0 = fmaxf(fmaf(a0, inv, bov.x), 0.f);
    float o1 = fmaxf(fmaf(a1, inv, bov.y), 0.f);
    float o2 = fmaxf(fmaf(a2, inv, bov.z), 0.f);
    float o3 = fmaxf(fmaf(a3, inv, bov.w), 0.f);
    uint2 pk;
    pk.x = (unsigned int)f2bf(o0) | ((unsigned int)f2bf(o1) << 16);
    pk.y = (unsigned int)f2bf(o2) | ((unsigned int)f2bf(o3) << 16);
    *(uint2*)(act + (size_t)n * DD + c0) = pk;

    float v1 = o0 + o1 + o2 + o3;
    float v2 = o0 * o0 + o1 * o1 + o2 * o2 + o3 * o3;
    #pragma unroll
    for (int off = 32; off > 0; off >>= 1) {
        v1 += __shfl_xor(v1, off, 64);
        v2 += __shfl_xor(v2, off, 64);
    }
    if (lane == 0) partial[n] = make_float2(v1, v2);
}

// ---------------- LN stats stage 1: 64-block partial reduce ----------------
__global__ __launch_bounds__(256) void k_lnreduce(const float2* __restrict__ partial,
                                                  double2* __restrict__ partial2) {
    int b = blockIdx.x, t = threadIdx.x;
    double s1 = 0.0, s2 = 0.0;
    for (int i = b * 256 + t; i < NN; i += 64 * 256) {
        float2 p = partial[i];
        s1 += p.x; s2 += p.y;
    }
    __shared__ double d1[256], d2[256];
    d1[t] = s1; d2[t] = s2;
    __syncthreads();
    for (int off = 128; off > 0; off >>= 1) {
        if (t < off) { d1[t] += d1[t + off]; d2[t] += d2[t + off]; }
        __syncthreads();
    }
    if (t == 0) partial2[b] = (double2){d1[0], d2[0]};
}

// ---------------- LN stats stage 2 ----------------
__global__ __launch_bounds__(256) void k_stats(const double2* __restrict__ partial2,
                                               const float* __restrict__ gamma, const float* __restrict__ beta,
                                               float* __restrict__ sc, float* __restrict__ vsh) {
    __shared__ double d1[64], d2[64];
    int t = threadIdx.x;
    if (t < 64) { double2 p = partial2[t]; d1[t] = p.x; d2[t] = p.y; }
    __syncthreads();
    for (int off = 32; off > 0; off >>= 1) {
        if (t < off) { d1[t] += d1[t + off]; d2[t] += d2[t + off]; }
        __syncthreads();
    }
    const double M = (double)NN * DD;
    double mu = d1[0] / M;
    double var = d2[0] / M - mu * mu;
    float rs = rsqrtf((float)(var + 1e-5));
    float scv = rs * gamma[t];
    sc[t] = scv;
    vsh[t] = beta[t] - (float)mu * scv;
}

// ---------------- fold LN into next layer's weights ----------------
__global__ __launch_bounds__(256) void k_foldw(const unsigned short* __restrict__ Wct,
                                               const float* __restrict__ bcL,
                                               const float* __restrict__ sc, const float* __restrict__ vsh,
                                               unsigned short* __restrict__ Wct2, float* __restrict__ bc2) {
    int row = (blockIdx.x << 2) + (threadIdx.x >> 6);  // 0..511
    int lane = threadIdx.x & 63;
    int k0 = lane * 4;
    uint2 raw = *(const uint2*)(Wct + (size_t)row * DD + k0);
    float w0 = bf2f((unsigned short)(raw.x & 0xffff));
    float w1 = bf2f((unsigned short)(raw.x >> 16));
    float w2 = bf2f((unsigned short)(raw.y & 0xffff));
    float w3 = bf2f((unsigned short)(raw.y >> 16));
    float4 scv = *(const float4*)(sc + k0);
    float4 vv  = *(const float4*)(vsh + k0);
    uint2 pk;
    pk.x = (unsigned int)f2bf(w0 * scv.x) | ((unsigned int)f2bf(w1 * scv.y) << 16);
    pk.y = (unsigned int)f2bf(w2 * scv.z) | ((unsigned int)f2bf(w3 * scv.w) << 16);
    *(uint2*)(Wct2 + (size_t)row * DD + k0) = pk;
    float d = w0 * vv.x + w1 * vv.y + w2 * vv.z + w3 * vv.w;
    #pragma unroll
    for (int off = 32; off > 0; off >>= 1) d += __shfl_xor(d, off, 64);
    if (lane == 0) bc2[row] = bcL[row] + d;
}

// ---------------- final output: h = act*sc + vsh (fp32) ----------------
__global__ __launch_bounds__(256) void k_final(const unsigned short* __restrict__ act,
                                               const float* __restrict__ sc, const float* __restrict__ vsh,
                                               float* __restrict__ h) {
    size_t i = ((size_t)blockIdx.x * 256 + threadIdx.x) * 4;
    uint2 raw = *(const uint2*)(act + i);
    int ch = (int)(i & (DD - 1));
    float4 scv = *(const float4*)(sc + ch);
    float4 vv  = *(const float4*)(vsh + ch);
    float4 o;
    o.x = fmaf(bf2f((unsigned short)(raw.x & 0xffff)), scv.x, vv.x);
    o.y = fmaf(bf2f((unsigned short)(raw.x >> 16)),    scv.y, vv.y);
    o.z = fmaf(bf2f((unsigned short)(raw.y & 0xffff)), scv.z, vv.z);
    o.w = fmaf(bf2f((unsigned short)(raw.y >> 16)),    scv.w, vv.w);
    *reinterpret_cast<float4*>(h + i) = o;
}

// ---------------- launch ----------------

extern "C" void kernel_launch(void* const* d_in, const int* in_sizes, int n_in,
                              void* d_out, int out_size, void* d_ws, size_t ws_size,
                              hipStream_t stream) {
    const float* x    = (const float*)d_in[0];
    const int*   ei   = (const int*)d_in[1];
    const int*   ety  = (const int*)d_in[2];
    const float* efe  = (const float*)d_in[3];
    const float* W0   = (const float*)d_in[4];
    const float* b0   = (const float*)d_in[5];
    const float* Wl   = (const float*)d_in[6];
    const float* bl   = (const float*)d_in[7];
    const float* Wr   = (const float*)d_in[8];
    const float* br   = (const float*)d_in[9];
    const float* We   = (const float*)d_in[10];
    const float* att  = (const float*)d_in[11];
    const float* bo   = (const float*)d_in[12];
    const float* gamma= (const float*)d_in[13];
    const float* beta = (const float*)d_in[14];
    float* h = (float*)d_out;

    char* base = (char*)d_ws;
    size_t off = 0;
    auto carve = [&](size_t bytes) -> void* {
        void* p = base + off;
        off += (bytes + 255) & ~(size_t)255;
        return p;
    };
    unsigned short* act  = (unsigned short*)carve((size_t)MPAD * DD * 2);
    unsigned short* xlr  = (unsigned short*)carve((size_t)NN * 512 * 2);
    unsigned short* Wct  = (unsigned short*)carve((size_t)LL * 512 * DD * 2);
    unsigned short* Wct2 = (unsigned short*)carve((size_t)512 * DD * 2);
    float* bc            = (float*)carve((size_t)LL * 512 * 4);
    float* bc2           = (float*)carve((size_t)512 * 4);
    float* sc            = (float*)carve((size_t)DD * 4);
    float* vsh           = (float*)carve((size_t)DD * 4);
    int*   deg      = (int*)carve((size_t)NN * 4);
    int*   offsets  = (int*)carve((size_t)(NN + 1) * 4);
    int*   bsum     = (int*)carve(1024);
    int*   boff     = (int*)carve(1024);
    int*   csr_src  = (int*)carve((size_t)EE * 4);
    float* csr_feat = (float*)carve((size_t)EE * 4);
    float2* partial = (float2*)carve((size_t)NN * 8);
    double2* partial2 = (double2*)carve((size_t)64 * 16);

    const int NB = (NN + SCAN_CHUNK - 1) / SCAN_CHUNK;

    // CSR build
    hipMemsetAsync(deg, 0, (size_t)NN * 4, stream);
    k_count<<<(EE + 255) / 256, 256, 0, stream>>>(ei + EE, deg, EE);
    k_scan1<<<NB, 256, 0, stream>>>(deg, bsum, NN);
    k_scan2<<<1, 64, 0, stream>>>(bsum, boff, NB, offsets, NN);
    k_scan3<<<NB, 256, 0, stream>>>(deg, boff, offsets, NN);
    hipMemsetAsync(deg, 0, (size_t)NN * 4, stream);
    k_fill<<<(EE + 255) / 256, 256, 0, stream>>>(ei, ei + EE, ety, efe, offsets, deg,
                                                 csr_src, csr_feat, EE);

    // weights -> bf16 B^T layout; bias concat
    k_cvtw<<<dim3(4, 4, 6), 256, 0, stream>>>(Wl, Wr, Wct);
    k_bias<<<6, 256, 0, stream>>>(bl, br, bc);

    // pre-encoder
    k_preenc<<<NN / 8, 256, 0, stream>>>(x, W0, b0, act);

    for (int l = 0; l < LL; l++) {
        const unsigned short* Wg = (l == 0) ? Wct : Wct2;
        const float* bg = (l == 0) ? bc : bc2;
        k_gemm<<<MPAD / 64, 512, 0, stream>>>(act, Wg, bg, xlr);
        k_aggregate<<<NN / 4, 256, 0, stream>>>(xlr, offsets, csr_src, csr_feat,
                                                We + (size_t)l * 4 * DD, att + (size_t)l * HH * CC,
                                                bo + (size_t)l * DD, act, partial);
        k_lnreduce<<<64, 256, 0, stream>>>(partial, partial2);
        k_stats<<<1, 256, 0, stream>>>(partial2, gamma, beta, sc, vsh);
        if (l < LL - 1)
            k_foldw<<<128, 256, 0, stream>>>(Wct + (size_t)(l + 1) * 512 * DD, bc + (size_t)(l + 1) * 512,
                                             sc, vsh, Wct2, bc2);
    }
    k_final<<<(NN * DD / 4) / 256, 256, 0, stream>>>(act, sc, vsh, h);
}

// Round 20
// 493.675 us; speedup vs baseline: 1.1218x; 1.0425x over previous
//
#include <hip/hip_runtime.h>
#include <hip/hip_bf16.h>

#define NN 100000
#define EE 300000
#define DD 256
#define HH 4
#define CC 64
#define LL 3
#define SCAN_CHUNK 1024

#define BM 64
#define BK 128
#define MPAD 100096   // 1564*64, padded row count for act

typedef __attribute__((ext_vector_type(8))) short bh8;    // 8 bf16 = 4 VGPR
typedef __attribute__((ext_vector_type(4))) float f32x4;

__device__ inline float bf2f(unsigned short u) {
    union { float f; unsigned int i; } c; c.i = ((unsigned int)u) << 16; return c.f;
}
__device__ inline unsigned short f2bf(float x) {
    __hip_bfloat16 b = __float2bfloat16(x);
    return *reinterpret_cast<unsigned short*>(&b);
}

// quad-local xor-1 + xor-2 sum via DPP quad_perm (no LDS, bitwise-uniform)
__device__ __forceinline__ float qsum2(float x) {
    x += __int_as_float(__builtin_amdgcn_update_dpp(0, __float_as_int(x), 0xB1, 0xF, 0xF, true)); // quad_perm [1,0,3,2] = xor1
    x += __int_as_float(__builtin_amdgcn_update_dpp(0, __float_as_int(x), 0x4E, 0xF, 0xF, true)); // quad_perm [2,3,0,1] = xor2
    return x;
}

// ---------------- CSR build ----------------

__global__ __launch_bounds__(256) void k_count(const int* __restrict__ dst, int* __restrict__ deg, int E_) {
    int e = blockIdx.x * 256 + threadIdx.x;
    if (e < E_) atomicAdd(&deg[dst[e]], 1);
}

__global__ __launch_bounds__(256) void k_scan1(const int* __restrict__ deg, int* __restrict__ bsum, int n) {
    int b = blockIdx.x;
    int base = b * SCAN_CHUNK;
    int t = threadIdx.x;
    int s = 0;
    for (int i = t; i < SCAN_CHUNK; i += 256) {
        int idx = base + i;
        if (idx < n) s += deg[idx];
    }
    __shared__ int sdata[256];
    sdata[t] = s;
    __syncthreads();
    for (int off = 128; off > 0; off >>= 1) {
        if (t < off) sdata[t] += sdata[t + off];
        __syncthreads();
    }
    if (t == 0) bsum[b] = sdata[0];
}

__global__ void k_scan2(const int* __restrict__ bsum, int* __restrict__ boff, int nb,
                        int* __restrict__ offsets, int n) {
    if (threadIdx.x == 0 && blockIdx.x == 0) {
        int run = 0;
        for (int i = 0; i < nb; i++) { boff[i] = run; run += bsum[i]; }
        offsets[n] = run;
    }
}

__global__ __launch_bounds__(256) void k_scan3(const int* __restrict__ deg, const int* __restrict__ boff,
                                               int* __restrict__ offsets, int n) {
    int b = blockIdx.x, t = threadIdx.x;
    int base = b * SCAN_CHUNK;
    int i0 = base + t * 4;
    int v[4]; int sum = 0;
    #pragma unroll
    for (int j = 0; j < 4; j++) {
        int idx = i0 + j;
        v[j] = (idx < n) ? deg[idx] : 0;
        sum += v[j];
    }
    __shared__ int sdata[256];
    sdata[t] = sum;
    __syncthreads();
    for (int off = 1; off < 256; off <<= 1) {
        int x = (t >= off) ? sdata[t - off] : 0;
        __syncthreads();
        sdata[t] += x;
        __syncthreads();
    }
    int excl = (t == 0) ? 0 : sdata[t - 1];
    int run = boff[b] + excl;
    #pragma unroll
    for (int j = 0; j < 4; j++) {
        int idx = i0 + j;
        if (idx < n) offsets[idx] = run;
        run += v[j];
    }
}

__global__ __launch_bounds__(256) void k_fill(const int* __restrict__ src, const int* __restrict__ dst,
                                              const int* __restrict__ ety, const float* __restrict__ efe,
                                              const int* __restrict__ offsets, int* __restrict__ cursor,
                                              int* __restrict__ csr_src, float* __restrict__ csr_feat, int E_) {
    int e = blockIdx.x * 256 + threadIdx.x;
    if (e < E_) {
        int d = dst[e];
        int pos = offsets[d] + atomicAdd(&cursor[d], 1);
        csr_src[pos] = src[e] | (ety[e] << 24);
        csr_feat[pos] = efe[e];
    }
}

// ---------------- weight prep: Wct[l][n][k] = W[l][k][n] as bf16 ----------------
__global__ __launch_bounds__(256) void k_cvtw(const float* __restrict__ Wl, const float* __restrict__ Wr,
                                              unsigned short* __restrict__ Wct) {
    int mat = blockIdx.z;
    int layer = mat >> 1, which = mat & 1;
    const float* src = (which ? Wr : Wl) + (size_t)layer * DD * DD;
    unsigned short* dst = Wct + (size_t)layer * 512 * DD + (size_t)which * DD * DD;
    int k0 = blockIdx.x * 64, n0 = blockIdx.y * 64;
    __shared__ float tile[64][65];
    int tx = threadIdx.x & 63, ty = threadIdx.x >> 6;
    #pragma unroll
    for (int i = 0; i < 16; i++) {
        int r = i * 4 + ty;
        tile[r][tx] = src[(size_t)(k0 + r) * DD + n0 + tx];
    }
    __syncthreads();
    #pragma unroll
    for (int i = 0; i < 16; i++) {
        int r = i * 4 + ty;
        dst[(size_t)(n0 + r) * DD + k0 + tx] = f2bf(tile[tx][r]);
    }
}

__global__ __launch_bounds__(256) void k_bias(const float* __restrict__ bl, const float* __restrict__ br,
                                              float* __restrict__ bc) {
    int i = blockIdx.x * 256 + threadIdx.x;
    if (i < LL * 512) {
        int l = i >> 9, j = i & 511;
        bc[i] = (j < 256) ? bl[l * DD + j] : br[l * DD + j - 256];
    }
}

// ---------------- pre-encoder: act = bf16(relu(x @ W0 + b0)) ----------------
__global__ __launch_bounds__(256) void k_preenc(const float* __restrict__ x, const float* __restrict__ W0,
                                                const float* __restrict__ b0, unsigned short* __restrict__ act) {
    __shared__ float xs[8][32];
    int t = threadIdx.x;
    int nb = blockIdx.x * 8;
    {
        int m = t >> 5, k = t & 31;
        xs[m][k] = x[(size_t)(nb + m) * 32 + k];
    }
    __syncthreads();
    float acc[8];
    float b = b0[t];
    #pragma unroll
    for (int m = 0; m < 8; m++) acc[m] = b;
    for (int k = 0; k < 32; k++) {
        float w = W0[k * DD + t];
        #pragma unroll
        for (int m = 0; m < 8; m++) acc[m] += xs[m][k] * w;
    }
    #pragma unroll
    for (int m = 0; m < 8; m++) {
        act[(size_t)(nb + m) * DD + t] = f2bf(fmaxf(acc[m], 0.f));
    }
}

// ---------------- MFMA GEMM v9 (champion): xlr[M,512] = act[M,256] @ Weff^T + beff ----------------
// BM=64 x full-N=512, BK=128 (2 k-phases; each barrier drains vmcnt(0) and
// exposes ~940cy convoy, so fewer phases = faster; measured v2->v9 71->66us).
__global__ __launch_bounds__(512) void k_gemm(const unsigned short* __restrict__ act,
                                              const unsigned short* __restrict__ Wct,
                                              const float* __restrict__ bc,
                                              unsigned short* __restrict__ xlr) {
    __shared__ short As[BM][136];                  // 17408 B
    __shared__ short Bs[512][136];                 // 139264 B; reused as stage[64][544]
    short* stage = &Bs[0][0];
    int t = threadIdx.x;
    int lane = t & 63;
    int w = t >> 6;                                // 0..7 : col chunk
    size_t rowBase = (size_t)blockIdx.x * BM;
    int rsel = lane & 15, kq = lane >> 4;

    f32x4 acc[4][4];
    #pragma unroll
    for (int i = 0; i < 4; i++)
        #pragma unroll
        for (int j = 0; j < 4; j++)
            acc[i][j] = (f32x4){0.f, 0.f, 0.f, 0.f};

    for (int ks = 0; ks < 2; ++ks) {
        __syncthreads();
        #pragma unroll
        for (int j = 0; j < 2; ++j) {   // A: 64 rows x 16 chunks = 1024 chunks, 2/thread
            int idx = t + j * 512;
            int row = idx >> 4, c16 = idx & 15;
            *(bh8*)&As[row][c16 * 8] =
                *(const bh8*)(act + (rowBase + row) * DD + ks * BK + c16 * 8);
        }
        #pragma unroll
        for (int j = 0; j < 16; ++j) {  // B: 512 rows x 16 chunks = 8192 chunks, 16/thread
            int idx = t + j * 512;
            int row = idx >> 4, c16 = idx & 15;
            *(bh8*)&Bs[row][c16 * 8] =
                *(const bh8*)(Wct + (size_t)row * DD + ks * BK + c16 * 8);
        }
        __syncthreads();
        #pragma unroll
        for (int kk = 0; kk < BK; kk += 32) {
            bh8 af[4], bfr[4];
            int ksel = kk + kq * 8;
            #pragma unroll
            for (int mi = 0; mi < 4; mi++)
                af[mi] = *(const bh8*)&As[mi * 16 + rsel][ksel];
            #pragma unroll
            for (int ni = 0; ni < 4; ni++)
                bfr[ni] = *(const bh8*)&Bs[w * 64 + ni * 16 + rsel][ksel];
            #pragma unroll
            for (int mi = 0; mi < 4; mi++)
                #pragma unroll
                for (int ni = 0; ni < 4; ni++)
                    acc[mi][ni] = __builtin_amdgcn_mfma_f32_16x16x32_bf16(af[mi], bfr[ni], acc[mi][ni], 0, 0, 0);
        }
    }

    __syncthreads();
    #pragma unroll
    for (int ni = 0; ni < 4; ni++) {
        int col = w * 64 + ni * 16 + rsel;
        float bias = bc[col];
        #pragma unroll
        for (int mi = 0; mi < 4; mi++) {
            int r0 = mi * 16 + kq * 4;
            #pragma unroll
            for (int j = 0; j < 4; j++)
                stage[(r0 + j) * 544 + col] = (short)f2bf(acc[mi][ni][j] + bias);
        }
    }
    __syncthreads();
    #pragma unroll
    for (int j = 0; j < 8; ++j) {       // 64 rows x 64 chunks(16B) = 4096, 8 per thread
        int idx = t + j * 512;
        int row = idx >> 6, c16 = idx & 63;
        size_t grow = rowBase + row;
        if (grow < NN)
            *(bh8*)(xlr + grow * 512 + c16 * 8) = *(const bh8*)&stage[row * 544 + c16 * 8];
    }
}

// ---------------- aggregation: 1 wave/node, 4 ch/lane, LDS ty-LUT + DPP reduce ----------------
// VALU-issue-bound (R19: VALUBusy 71%, FETCH at unique-data floor). Two cuts:
// (1) per-wave LDS LUT lut[ty][c] = xr + We[ty] -> 1 ds_read_b128 replaces the
//     2 v_cmp + 8 v_cndmask select chain per edge;
// (2) xor-1/2 reduce levels via DPP quad_perm adds (no DS, no lgkm wait);
//     shfl only for xor-4/8. LN wave-reduce likewise.
__global__ __launch_bounds__(256) void k_aggregate(const unsigned short* __restrict__ xlr,
                                                   const int* __restrict__ offsets,
                                                   const int* __restrict__ csr_src, const float* __restrict__ csr_feat,
                                                   const float* __restrict__ We, const float* __restrict__ att,
                                                   const float* __restrict__ bo,
                                                   unsigned short* __restrict__ act, float2* __restrict__ partial) {
    __shared__ __align__(16) float lut[4 * 768];   // [wave][ty][256] = 12288 B
    int lane = threadIdx.x & 63;
    int wid = threadIdx.x >> 6;
    int n = blockIdx.x * 4 + wid;
    int c0 = lane * 4;
    float* myl = &lut[wid * 768];

    float4 attv = *(const float4*)(att + c0);
    float4 we3 = *(const float4*)(We + 3 * DD + c0);
    float4 w0v = *(const float4*)(We + 0 * DD + c0);
    float4 w1v = *(const float4*)(We + 1 * DD + c0);
    float4 w2v = *(const float4*)(We + 2 * DD + c0);

    uint2 xrr = *(const uint2*)(xlr + (size_t)n * 512 + 256 + c0);
    float xr0 = bf2f((unsigned short)(xrr.x & 0xffff));
    float xr1 = bf2f((unsigned short)(xrr.x >> 16));
    float xr2 = bf2f((unsigned short)(xrr.y & 0xffff));
    float xr3 = bf2f((unsigned short)(xrr.y >> 16));

    // per-node LUT: base[ty] = xr + We[ty]  (same-wave produce/consume, no barrier)
    *(float4*)&myl[c0]        = make_float4(xr0 + w0v.x, xr1 + w0v.y, xr2 + w0v.z, xr3 + w0v.w);
    *(float4*)&myl[256 + c0]  = make_float4(xr0 + w1v.x, xr1 + w1v.y, xr2 + w1v.z, xr3 + w1v.w);
    *(float4*)&myl[512 + c0]  = make_float4(xr0 + w2v.x, xr1 + w2v.y, xr2 + w2v.z, xr3 + w2v.w);

    int start = offsets[n], end = offsets[n + 1];
    float s = 0.f, a0 = 0.f, a1 = 0.f, a2 = 0.f, a3 = 0.f;
    int i = start;
    for (; i + 2 <= end; i += 2) {
        int pA = csr_src[i];     float fA = csr_feat[i];
        int pB = csr_src[i + 1]; float fB = csr_feat[i + 1];
        uint2 xvA = *(const uint2*)(xlr + (size_t)(pA & 0xFFFFF) * 512 + c0);
        uint2 xvB = *(const uint2*)(xlr + (size_t)(pB & 0xFFFFF) * 512 + c0);
        float4 sA = *(const float4*)&myl[(pA >> 24) * 256 + c0];
        float4 sB = *(const float4*)&myl[(pB >> 24) * 256 + c0];
        float xA0 = bf2f((unsigned short)(xvA.x & 0xffff));
        float xA1 = bf2f((unsigned short)(xvA.x >> 16));
        float xA2 = bf2f((unsigned short)(xvA.y & 0xffff));
        float xA3 = bf2f((unsigned short)(xvA.y >> 16));
        float xB0 = bf2f((unsigned short)(xvB.x & 0xffff));
        float xB1 = bf2f((unsigned short)(xvB.x >> 16));
        float xB2 = bf2f((unsigned short)(xvB.y & 0xffff));
        float xB3 = bf2f((unsigned short)(xvB.y >> 16));
        float eA0 = xA0 + fmaf(fA, we3.x, sA.x); eA0 = fmaxf(eA0, 0.2f * eA0);
        float eA1 = xA1 + fmaf(fA, we3.y, sA.y); eA1 = fmaxf(eA1, 0.2f * eA1);
        float eA2 = xA2 + fmaf(fA, we3.z, sA.z); eA2 = fmaxf(eA2, 0.2f * eA2);
        float eA3 = xA3 + fmaf(fA, we3.w, sA.w); eA3 = fmaxf(eA3, 0.2f * eA3);
        float eB0 = xB0 + fmaf(fB, we3.x, sB.x); eB0 = fmaxf(eB0, 0.2f * eB0);
        float eB1 = xB1 + fmaf(fB, we3.y, sB.y); eB1 = fmaxf(eB1, 0.2f * eB1);
        float eB2 = xB2 + fmaf(fB, we3.z, sB.z); eB2 = fmaxf(eB2, 0.2f * eB2);
        float eB3 = xB3 + fmaf(fB, we3.w, sB.w); eB3 = fmaxf(eB3, 0.2f * eB3);
        float dA = attv.x * eA0 + attv.y * eA1 + attv.z * eA2 + attv.w * eA3;
        float dB = attv.x * eB0 + attv.y * eB1 + attv.z * eB2 + attv.w * eB3;
        dA = qsum2(dA);               dB = qsum2(dB);
        dA += __shfl_xor(dA, 4, 64);  dB += __shfl_xor(dB, 4, 64);
        dA += __shfl_xor(dA, 8, 64);  dB += __shfl_xor(dB, 8, 64);
        float pa = __expf(fminf(fmaxf(dA, -60.f), 60.f));
        float pb = __expf(fminf(fmaxf(dB, -60.f), 60.f));
        s += pa + pb;
        a0 = fmaf(pa, xA0, fmaf(pb, xB0, a0));
        a1 = fmaf(pa, xA1, fmaf(pb, xB1, a1));
        a2 = fmaf(pa, xA2, fmaf(pb, xB2, a2));
        a3 = fmaf(pa, xA3, fmaf(pb, xB3, a3));
    }
    if (i < end) {
        int pA = csr_src[i]; float fA = csr_feat[i];
        uint2 xvA = *(const uint2*)(xlr + (size_t)(pA & 0xFFFFF) * 512 + c0);
        float4 sA = *(const float4*)&myl[(pA >> 24) * 256 + c0];
        float xA0 = bf2f((unsigned short)(xvA.x & 0xffff));
        float xA1 = bf2f((unsigned short)(xvA.x >> 16));
        float xA2 = bf2f((unsigned short)(xvA.y & 0xffff));
        float xA3 = bf2f((unsigned short)(xvA.y >> 16));
        float eA0 = xA0 + fmaf(fA, we3.x, sA.x); eA0 = fmaxf(eA0, 0.2f * eA0);
        float eA1 = xA1 + fmaf(fA, we3.y, sA.y); eA1 = fmaxf(eA1, 0.2f * eA1);
        float eA2 = xA2 + fmaf(fA, we3.z, sA.z); eA2 = fmaxf(eA2, 0.2f * eA2);
        float eA3 = xA3 + fmaf(fA, we3.w, sA.w); eA3 = fmaxf(eA3, 0.2f * eA3);
        float dA = attv.x * eA0 + attv.y * eA1 + attv.z * eA2 + attv.w * eA3;
        dA = qsum2(dA);
        dA += __shfl_xor(dA, 4, 64);
        dA += __shfl_xor(dA, 8, 64);
        float pa = __expf(fminf(fmaxf(dA, -60.f), 60.f));
        s += pa;
        a0 = fmaf(pa, xA0, a0);
        a1 = fmaf(pa, xA1, a1);
        a2 = fmaf(pa, xA2, a2);
        a3 = fmaf(pa, xA3, a3);
    }
    float inv = (end > start) ? __builtin_amdgcn_rcpf(s) : 0.f;
    float4 bov = *(const float4*)(bo + c0);
    float o0 = fmaxf(fmaf(a0, inv, bov.x), 0.f);
    float o1 = fmaxf(fmaf(a1, inv, bov.y), 0.f);
    float o2 = fmaxf(fmaf(a2, inv, bov.z), 0.f);
    float o3 = fmaxf(fmaf(a3, inv, bov.w), 0.f);
    uint2 pk;
    pk.x = (unsigned int)f2bf(o0) | ((unsigned int)f2bf(o1) << 16);
    pk.y = (unsigned int)f2bf(o2) | ((unsigned int)f2bf(o3) << 16);
    *(uint2*)(act + (size_t)n * DD + c0) = pk;

    float v1 = o0 + o1 + o2 + o3;
    float v2 = o0 * o0 + o1 * o1 + o2 * o2 + o3 * o3;
    v1 = qsum2(v1); v2 = qsum2(v2);
    #pragma unroll
    for (int off = 4; off <= 32; off <<= 1) {
        v1 += __shfl_xor(v1, off, 64);
        v2 += __shfl_xor(v2, off, 64);
    }
    if (lane == 0) partial[n] = make_float2(v1, v2);
}

// ---------------- LN stats stage 1: 64-block partial reduce ----------------
__global__ __launch_bounds__(256) void k_lnreduce(const float2* __restrict__ partial,
                                                  double2* __restrict__ partial2) {
    int b = blockIdx.x, t = threadIdx.x;
    double s1 = 0.0, s2 = 0.0;
    for (int i = b * 256 + t; i < NN; i += 64 * 256) {
        float2 p = partial[i];
        s1 += p.x; s2 += p.y;
    }
    __shared__ double d1[256], d2[256];
    d1[t] = s1; d2[t] = s2;
    __syncthreads();
    for (int off = 128; off > 0; off >>= 1) {
        if (t < off) { d1[t] += d1[t + off]; d2[t] += d2[t + off]; }
        __syncthreads();
    }
    if (t == 0) partial2[b] = (double2){d1[0], d2[0]};
}

// ---------------- LN stats stage 2 ----------------
__global__ __launch_bounds__(256) void k_stats(const double2* __restrict__ partial2,
                                               const float* __restrict__ gamma, const float* __restrict__ beta,
                                               float* __restrict__ sc, float* __restrict__ vsh) {
    __shared__ double d1[64], d2[64];
    int t = threadIdx.x;
    if (t < 64) { double2 p = partial2[t]; d1[t] = p.x; d2[t] = p.y; }
    __syncthreads();
    for (int off = 32; off > 0; off >>= 1) {
        if (t < off) { d1[t] += d1[t + off]; d2[t] += d2[t + off]; }
        __syncthreads();
    }
    const double M = (double)NN * DD;
    double mu = d1[0] / M;
    double var = d2[0] / M - mu * mu;
    float rs = rsqrtf((float)(var + 1e-5));
    float scv = rs * gamma[t];
    sc[t] = scv;
    vsh[t] = beta[t] - (float)mu * scv;
}

// ---------------- fold LN into next layer's weights ----------------
__global__ __launch_bounds__(256) void k_foldw(const unsigned short* __restrict__ Wct,
                                               const float* __restrict__ bcL,
                                               const float* __restrict__ sc, const float* __restrict__ vsh,
                                               unsigned short* __restrict__ Wct2, float* __restrict__ bc2) {
    int row = (blockIdx.x << 2) + (threadIdx.x >> 6);  // 0..511
    int lane = threadIdx.x & 63;
    int k0 = lane * 4;
    uint2 raw = *(const uint2*)(Wct + (size_t)row * DD + k0);
    float w0 = bf2f((unsigned short)(raw.x & 0xffff));
    float w1 = bf2f((unsigned short)(raw.x >> 16));
    float w2 = bf2f((unsigned short)(raw.y & 0xffff));
    float w3 = bf2f((unsigned short)(raw.y >> 16));
    float4 scv = *(const float4*)(sc + k0);
    float4 vv  = *(const float4*)(vsh + k0);
    uint2 pk;
    pk.x = (unsigned int)f2bf(w0 * scv.x) | ((unsigned int)f2bf(w1 * scv.y) << 16);
    pk.y = (unsigned int)f2bf(w2 * scv.z) | ((unsigned int)f2bf(w3 * scv.w) << 16);
    *(uint2*)(Wct2 + (size_t)row * DD + k0) = pk;
    float d = w0 * vv.x + w1 * vv.y + w2 * vv.z + w3 * vv.w;
    #pragma unroll
    for (int off = 32; off > 0; off >>= 1) d += __shfl_xor(d, off, 64);
    if (lane == 0) bc2[row] = bcL[row] + d;
}

// ---------------- final output: h = act*sc + vsh (fp32) ----------------
__global__ __launch_bounds__(256) void k_final(const unsigned short* __restrict__ act,
                                               const float* __restrict__ sc, const float* __restrict__ vsh,
                                               float* __restrict__ h) {
    size_t i = ((size_t)blockIdx.x * 256 + threadIdx.x) * 4;
    uint2 raw = *(const uint2*)(act + i);
    int ch = (int)(i & (DD - 1));
    float4 scv = *(const float4*)(sc + ch);
    float4 vv  = *(const float4*)(vsh + ch);
    float4 o;
    o.x = fmaf(bf2f((unsigned short)(raw.x & 0xffff)), scv.x, vv.x);
    o.y = fmaf(bf2f((unsigned short)(raw.x >> 16)),    scv.y, vv.y);
    o.z = fmaf(bf2f((unsigned short)(raw.y & 0xffff)), scv.z, vv.z);
    o.w = fmaf(bf2f((unsigned short)(raw.y >> 16)),    scv.w, vv.w);
    *reinterpret_cast<float4*>(h + i) = o;
}

// ---------------- launch ----------------

extern "C" void kernel_launch(void* const* d_in, const int* in_sizes, int n_in,
                              void* d_out, int out_size, void* d_ws, size_t ws_size,
                              hipStream_t stream) {
    const float* x    = (const float*)d_in[0];
    const int*   ei   = (const int*)d_in[1];
    const int*   ety  = (const int*)d_in[2];
    const float* efe  = (const float*)d_in[3];
    const float* W0   = (const float*)d_in[4];
    const float* b0   = (const float*)d_in[5];
    const float* Wl   = (const float*)d_in[6];
    const float* bl   = (const float*)d_in[7];
    const float* Wr   = (const float*)d_in[8];
    const float* br   = (const float*)d_in[9];
    const float* We   = (const float*)d_in[10];
    const float* att  = (const float*)d_in[11];
    const float* bo   = (const float*)d_in[12];
    const float* gamma= (const float*)d_in[13];
    const float* beta = (const float*)d_in[14];
    float* h = (float*)d_out;

    char* base = (char*)d_ws;
    size_t off = 0;
    auto carve = [&](size_t bytes) -> void* {
        void* p = base + off;
        off += (bytes + 255) & ~(size_t)255;
        return p;
    };
    unsigned short* act  = (unsigned short*)carve((size_t)MPAD * DD * 2);
    unsigned short* xlr  = (unsigned short*)carve((size_t)NN * 512 * 2);
    unsigned short* Wct  = (unsigned short*)carve((size_t)LL * 512 * DD * 2);
    unsigned short* Wct2 = (unsigned short*)carve((size_t)512 * DD * 2);
    float* bc            = (float*)carve((size_t)LL * 512 * 4);
    float* bc2           = (float*)carve((size_t)512 * 4);
    float* sc            = (float*)carve((size_t)DD * 4);
    float* vsh           = (float*)carve((size_t)DD * 4);
    int*   deg      = (int*)carve((size_t)NN * 4);
    int*   offsets  = (int*)carve((size_t)(NN + 1) * 4);
    int*   bsum     = (int*)carve(1024);
    int*   boff     = (int*)carve(1024);
    int*   csr_src  = (int*)carve((size_t)EE * 4);
    float* csr_feat = (float*)carve((size_t)EE * 4);
    float2* partial = (float2*)carve((size_t)NN * 8);
    double2* partial2 = (double2*)carve((size_t)64 * 16);

    const int NB = (NN + SCAN_CHUNK - 1) / SCAN_CHUNK;

    // CSR build
    hipMemsetAsync(deg, 0, (size_t)NN * 4, stream);
    k_count<<<(EE + 255) / 256, 256, 0, stream>>>(ei + EE, deg, EE);
    k_scan1<<<NB, 256, 0, stream>>>(deg, bsum, NN);
    k_scan2<<<1, 64, 0, stream>>>(bsum, boff, NB, offsets, NN);
    k_scan3<<<NB, 256, 0, stream>>>(deg, boff, offsets, NN);
    hipMemsetAsync(deg, 0, (size_t)NN * 4, stream);
    k_fill<<<(EE + 255) / 256, 256, 0, stream>>>(ei, ei + EE, ety, efe, offsets, deg,
                                                 csr_src, csr_feat, EE);

    // weights -> bf16 B^T layout; bias concat
    k_cvtw<<<dim3(4, 4, 6), 256, 0, stream>>>(Wl, Wr, Wct);
    k_bias<<<6, 256, 0, stream>>>(bl, br, bc);

    // pre-encoder
    k_preenc<<<NN / 8, 256, 0, stream>>>(x, W0, b0, act);

    for (int l = 0; l < LL; l++) {
        const unsigned short* Wg = (l == 0) ? Wct : Wct2;
        const float* bg = (l == 0) ? bc : bc2;
        k_gemm<<<MPAD / 64, 512, 0, stream>>>(act, Wg, bg, xlr);
        k_aggregate<<<NN / 4, 256, 0, stream>>>(xlr, offsets, csr_src, csr_feat,
                                                We + (size_t)l * 4 * DD, att + (size_t)l * HH * CC,
                                                bo + (size_t)l * DD, act, partial);
        k_lnreduce<<<64, 256, 0, stream>>>(partial, partial2);
        k_stats<<<1, 256, 0, stream>>>(partial2, gamma, beta, sc, vsh);
        if (l < LL - 1)
            k_foldw<<<128, 256, 0, stream>>>(Wct + (size_t)(l + 1) * 512 * DD, bc + (size_t)(l + 1) * 512,
                                             sc, vsh, Wct2, bc2);
    }
    k_final<<<(NN * DD / 4) / 256, 256, 0, stream>>>(act, sc, vsh, h);
}